// Round 9
// baseline (189.641 us; speedup 1.0000x reference)
//
#include <hip/hip_runtime.h>
#include <hip/hip_bf16.h>
#include <stdint.h>

typedef __bf16 bf16;
typedef __bf16 bf16x4 __attribute__((ext_vector_type(4)));
typedef __bf16 bf16x8 __attribute__((ext_vector_type(8)));
typedef float f32x4 __attribute__((ext_vector_type(4)));
typedef float f32x16 __attribute__((ext_vector_type(16)));

#define D_MODEL 768
#define NUM_HEADS 48
#define HEAD_CH 16
#define INNER 2304
#define BATCH 2
#define SEQLEN 2048
#define M_ROWS (BATCH * SEQLEN)
#define EPSF 1e-6f
// S-tile stride (bf16). MUST be 0 mod 8 (16B row alignment for ds_read_b128).
#define SST 40

// async global->LDS, 16B per lane. LDS dest must be wave-uniform base + lane*16.
__device__ inline void gload_lds16(const void* g, void* l) {
  __builtin_amdgcn_global_load_lds((__attribute__((address_space(1))) void*)(g),
                                   (__attribute__((address_space(3))) void*)(l),
                                   16, 0, 0);
}

// XCD-aware bijective block remap (requires nwg % 8 == 0): consecutive
// hardware IDs round-robin XCDs; remap so each XCD owns a contiguous tile
// range -> neighbor tiles share an L2 (T1).
__device__ inline void xcd_swz(int& bx, int& by) {
  const int nx = gridDim.x;
  const int f = bx + nx * by;
  const int q = (nx * gridDim.y) >> 3;
  const int s = (f & 7) * q + (f >> 3);
  bx = s % nx;
  by = s / nx;
}

// ---------------------------------------------------------------------------
// fused dual f32 -> bf16 convert (two independent tensors, one launch)
// ---------------------------------------------------------------------------
__global__ __launch_bounds__(256) void cvt2_f32_bf16(
    const float* __restrict__ a, bf16* __restrict__ da, int na4,
    const float* __restrict__ b, bf16* __restrict__ db, int nb4) {
  int j = blockIdx.x * 256 + threadIdx.x;
  const float* s;
  bf16* d;
  if (j < na4) {
    s = a; d = da;
  } else {
    j -= na4;
    if (j >= nb4) return;
    s = b; d = db;
  }
  const float4 v = ((const float4*)s)[j];
  bf16x4 o;
  o[0] = (bf16)v.x; o[1] = (bf16)v.y; o[2] = (bf16)v.z; o[3] = (bf16)v.w;
  ((bf16x4*)d)[j] = o;
}

// ---------------------------------------------------------------------------
// w_out * norm_w  f32 -> bf16 (norm_w folded along the contraction dim d)
// ---------------------------------------------------------------------------
__global__ __launch_bounds__(256) void cvt_wout_nw(
    const float* __restrict__ src, const float* __restrict__ nw,
    bf16* __restrict__ dst, int n4) {
  const int i = blockIdx.x * 256 + threadIdx.x;
  if (i < n4) {
    const int d0 = (i * 4) % D_MODEL;
    const float4 v = ((const float4*)src)[i];
    const float4 nv = *(const float4*)&nw[d0];
    bf16x4 o;
    o[0] = (bf16)(v.x * nv.x); o[1] = (bf16)(v.y * nv.y);
    o[2] = (bf16)(v.z * nv.z); o[3] = (bf16)(v.w * nv.w);
    ((bf16x4*)dst)[i] = o;
  }
}

// ---------------------------------------------------------------------------
// GEMM1: C[m,n] = sum_k A[m,k]*W[n,k] + bias[n]; m97 pattern, 128x128, BK=64.
// ---------------------------------------------------------------------------
template <int TM, int TN, int BK, int NCOLS, typename CT>
__global__ __launch_bounds__(256) void gemm_bt(
    const bf16* __restrict__ A, const bf16* __restrict__ W,
    const float* __restrict__ bias, CT* __restrict__ C, int K) {
  constexpr int MI = TM / 32;
  constexpr int NI = TN / 32;
  constexpr int KK = BK / 32;
  __shared__ __align__(16) bf16 As[TM * BK];
  __shared__ __align__(16) bf16 Bs[TN * BK];
  const int t = threadIdx.x;
  const int lane = t & 63, w = t >> 6;
  const int wm = (w >> 1) * (TM / 2), wn = (w & 1) * (TN / 2);
  const int row16 = lane & 15, quad = lane >> 4;
  int bx = blockIdx.x, by = blockIdx.y;
  xcd_swz(bx, by);
  const int m0 = bx * TM, n0 = by * TN;

  f32x4 zero4 = {0.f, 0.f, 0.f, 0.f};
  f32x4 acc[MI][NI];
#pragma unroll
  for (int mi = 0; mi < MI; ++mi)
#pragma unroll
    for (int ni = 0; ni < NI; ++ni) acc[mi][ni] = zero4;

  const int arow = t >> 2;        // 0..63
  const int acol = (t & 3) * 8;   // 0..24
  const bf16* Ab = A + (size_t)m0 * K;
  const bf16* Wb = W + (size_t)n0 * K;

  for (int kt = 0; kt < K; kt += BK) {
#pragma unroll
    for (int kk0 = 0; kk0 < KK; ++kk0) {
#pragma unroll
      for (int rh = 0; rh < TM / 64; ++rh)
        gload_lds16(Ab + (size_t)(rh * 64 + arow) * K + kt + kk0 * 32 + acol,
                    As + kk0 * (TM * 32) + rh * 2048 + t * 8);
#pragma unroll
      for (int rh = 0; rh < TN / 64; ++rh)
        gload_lds16(Wb + (size_t)(rh * 64 + arow) * K + kt + kk0 * 32 + acol,
                    Bs + kk0 * (TN * 32) + rh * 2048 + t * 8);
    }
    __syncthreads();

    bf16x8 af[MI][KK], wf[NI][KK];
#pragma unroll
    for (int kk0 = 0; kk0 < KK; ++kk0) {
#pragma unroll
      for (int mi = 0; mi < MI; ++mi)
        af[mi][kk0] = *(const bf16x8*)&As[kk0 * (TM * 32) +
                                          (wm + mi * 16 + row16) * 32 +
                                          quad * 8];
#pragma unroll
      for (int ni = 0; ni < NI; ++ni)
        wf[ni][kk0] = *(const bf16x8*)&Bs[kk0 * (TN * 32) +
                                          (wn + ni * 16 + row16) * 32 +
                                          quad * 8];
    }
#pragma unroll
    for (int kk0 = 0; kk0 < KK; ++kk0)
#pragma unroll
      for (int mi = 0; mi < MI; ++mi)
#pragma unroll
        for (int ni = 0; ni < NI; ++ni)
          acc[mi][ni] = __builtin_amdgcn_mfma_f32_16x16x32_bf16(
              af[mi][kk0], wf[ni][kk0], acc[mi][ni], 0, 0, 0);
    __syncthreads();
  }

#pragma unroll
  for (int mi = 0; mi < MI; ++mi) {
#pragma unroll
    for (int ni = 0; ni < NI; ++ni) {
      const int col = n0 + wn + ni * 16 + row16;
      const float bv = bias[col];
#pragma unroll
      for (int r = 0; r < 4; ++r) {
        const int row = m0 + wm + mi * 16 + quad * 4 + r;
        C[(size_t)row * NCOLS + col] = (CT)(acc[mi][ni][r] + bv);
      }
    }
  }
}

// ---------------------------------------------------------------------------
// GEMM2 + fused RMSNorm, 128x64 tile (vs r8's 64x64: 2x per-wave MFMA work,
// half the barriers per FLOP). out[m,n] = r[m]*sum_k y[m,k]*W'[n,k] + b[n]
// + skip. W' = w_out*nw. r[m] from the staged A-tiles.
// Waves: wm=(w>>1)*64, wn=(w&1)*32; per-wave 64x32 via 4x2 16x16 frags.
// ---------------------------------------------------------------------------
__global__ __launch_bounds__(256) void gemm_rms(
    const bf16* __restrict__ A, const bf16* __restrict__ W,
    const float* __restrict__ bias, const float* __restrict__ skip,
    float* __restrict__ C) {
  constexpr int TM = 128, TN = 64, BK = 64, K = D_MODEL;
  constexpr int MI = 4, NI = 2, KK = 2;
  __shared__ __align__(16) bf16 As[TM * BK];   // 16 KB, [kk0][128][32]
  __shared__ __align__(16) bf16 Bs[TN * BK];   // 8 KB,  [kk0][64][32]
  __shared__ float rs[TM];
  const int t = threadIdx.x;
  const int lane = t & 63, w = t >> 6;
  const int wm = (w >> 1) * 64, wn = (w & 1) * 32;
  const int row16 = lane & 15, quad = lane >> 4;
  int bx = blockIdx.x, by = blockIdx.y;
  xcd_swz(bx, by);
  const int m0 = bx * TM, n0 = by * TN;

  f32x4 zero4 = {0.f, 0.f, 0.f, 0.f};
  f32x4 acc[MI][NI];
#pragma unroll
  for (int mi = 0; mi < MI; ++mi)
#pragma unroll
    for (int ni = 0; ni < NI; ++ni) acc[mi][ni] = zero4;

  const int arow = t >> 2;       // 0..63
  const int acol = (t & 3) * 8;  // 0..24
  const bf16* Ab = A + (size_t)m0 * K;
  const bf16* Wb = W + (size_t)n0 * K;
  float ssq0 = 0.f, ssq1 = 0.f;  // rows arow, 64+arow

  for (int kt = 0; kt < K; kt += BK) {
#pragma unroll
    for (int kk0 = 0; kk0 < KK; ++kk0) {
#pragma unroll
      for (int rh = 0; rh < 2; ++rh)
        gload_lds16(Ab + (size_t)(rh * 64 + arow) * K + kt + kk0 * 32 + acol,
                    As + kk0 * (TM * 32) + rh * 2048 + t * 8);
      gload_lds16(Wb + (size_t)arow * K + kt + kk0 * 32 + acol,
                  Bs + kk0 * (TN * 32) + t * 8);
    }
    __syncthreads();

    bf16x8 af[MI][KK], wf[NI][KK];
#pragma unroll
    for (int kk0 = 0; kk0 < KK; ++kk0) {
#pragma unroll
      for (int mi = 0; mi < MI; ++mi)
        af[mi][kk0] = *(const bf16x8*)&As[kk0 * (TM * 32) +
                                          (wm + mi * 16 + row16) * 32 +
                                          quad * 8];
#pragma unroll
      for (int ni = 0; ni < NI; ++ni)
        wf[ni][kk0] = *(const bf16x8*)&Bs[kk0 * (TN * 32) +
                                          (wn + ni * 16 + row16) * 32 +
                                          quad * 8];
    }
    // ssq partials: exactly the elements this thread DMA'd
#pragma unroll
    for (int kk0 = 0; kk0 < KK; ++kk0) {
      const bf16x8 q0 = *(const bf16x8*)&As[kk0 * (TM * 32) + t * 8];
      const bf16x8 q1 = *(const bf16x8*)&As[kk0 * (TM * 32) + 2048 + t * 8];
#pragma unroll
      for (int jj = 0; jj < 8; ++jj) {
        const float f0 = (float)q0[jj], f1 = (float)q1[jj];
        ssq0 += f0 * f0;
        ssq1 += f1 * f1;
      }
    }
#pragma unroll
    for (int kk0 = 0; kk0 < KK; ++kk0)
#pragma unroll
      for (int mi = 0; mi < MI; ++mi)
#pragma unroll
        for (int ni = 0; ni < NI; ++ni)
          acc[mi][ni] = __builtin_amdgcn_mfma_f32_16x16x32_bf16(
              af[mi][kk0], wf[ni][kk0], acc[mi][ni], 0, 0, 0);
    __syncthreads();
  }

  // reduce ssq (4 threads per row, 2 row-halves) -> rs[0..127]
  float* ssr = (float*)As;  // As dead after loop (512 floats)
  ssr[t] = ssq0;
  ssr[256 + t] = ssq1;
  __syncthreads();
  if (t < TM) {
    const int base = (t < 64) ? 4 * t : 256 + 4 * (t - 64);
    const float s4 = ssr[base] + ssr[base + 1] + ssr[base + 2] + ssr[base + 3];
    rs[t] = rsqrtf(s4 * (1.f / (float)D_MODEL) + EPSF);
  }
  __syncthreads();

#pragma unroll
  for (int mi = 0; mi < MI; ++mi) {
#pragma unroll
    for (int ni = 0; ni < NI; ++ni) {
      const int col = n0 + wn + ni * 16 + row16;
      const float bv = bias[col];
#pragma unroll
      for (int r = 0; r < 4; ++r) {
        const int rowl = wm + mi * 16 + quad * 4 + r;
        const int row = m0 + rowl;
        C[(size_t)row * D_MODEL + col] =
            acc[mi][ni][r] * rs[rowl] + bv + skip[(size_t)row * D_MODEL + col];
      }
    }
  }
}

// ---------------------------------------------------------------------------
// Q+K+V causal width-3 conv from u (vectorized x4, r6-verified indexing):
//   ch 0..15  -> Q (B,N,L,16);  16..31 -> K (B,N,L,16);  32..47 -> V (B,N,16,L)
// ---------------------------------------------------------------------------
__global__ __launch_bounds__(256) void conv_qkv(
    const bf16* __restrict__ u, const float* __restrict__ w_sf,
    const float* __restrict__ b_sf, bf16* __restrict__ qq,
    bf16* __restrict__ kk, bf16* __restrict__ vv) {
  const int nh = blockIdx.x, b = blockIdx.y, lc = blockIdx.z;
  const int l0 = lc * 128;
  __shared__ __align__(8) bf16 ut[130 * 48];
  const int t = threadIdx.x;
  for (int i = t; i < 130 * 12; i += 256) {
    const int lr = i / 12, qd = i % 12;
    const int l = l0 - 2 + lr;
    uint2 val;
    val.x = 0u; val.y = 0u;
    if (l >= 0)
      val = *(const uint2*)&u[(size_t)(b * SEQLEN + l) * INNER + nh * 48 + qd * 4];
    *(uint2*)&ut[lr * 48 + qd * 4] = val;
  }
  __syncthreads();
  const size_t bn = (size_t)(b * NUM_HEADS + nh);
  // Q/K: 4 consecutive channels per work-item (float4 weight loads, 48B-
  // aligned since e0 % 4 == 0). 512 items each.
#pragma unroll
  for (int s = 0; s < 2; ++s) {
    bf16* dst = (s == 0) ? qq : kk;
    const int cb = s * 16;
    for (int i = t; i < 128 * 4; i += 256) {
      const int c4 = (i & 3) * 4, lr = i >> 2;
      const int e0 = nh * 48 + cb + c4;
      const float4 wa = *(const float4*)&w_sf[e0 * 3];
      const float4 wb = *(const float4*)&w_sf[e0 * 3 + 4];
      const float4 wc = *(const float4*)&w_sf[e0 * 3 + 8];
      const float4 bb = *(const float4*)&b_sf[e0];
      const bf16x4 u0 = *(const bf16x4*)&ut[lr * 48 + cb + c4];
      const bf16x4 u1 = *(const bf16x4*)&ut[(lr + 1) * 48 + cb + c4];
      const bf16x4 u2 = *(const bf16x4*)&ut[(lr + 2) * 48 + cb + c4];
      bf16x4 o;
      o[0] = (bf16)(wa.x * (float)u0[0] + wa.y * (float)u1[0] +
                    wa.z * (float)u2[0] + bb.x);
      o[1] = (bf16)(wa.w * (float)u0[1] + wb.x * (float)u1[1] +
                    wb.y * (float)u2[1] + bb.y);
      o[2] = (bf16)(wb.z * (float)u0[2] + wb.w * (float)u1[2] +
                    wc.x * (float)u2[2] + bb.z);
      o[3] = (bf16)(wc.y * (float)u0[3] + wc.z * (float)u1[3] +
                    wc.w * (float)u2[3] + bb.w);
      *(bf16x4*)&dst[(bn * SEQLEN + l0 + lr) * 16 + c4] = o;
    }
  }
  // V: 4 consecutive l per work-item. 512 items.
  for (int i = t; i < 16 * 32; i += 256) {
    const int c = i >> 5, lr4 = (i & 31) * 4;
    const int e = nh * 48 + 32 + c;
    const float w0 = w_sf[e * 3 + 0], w1 = w_sf[e * 3 + 1],
                w2 = w_sf[e * 3 + 2], bv = b_sf[e];
    bf16x4 o;
#pragma unroll
    for (int k = 0; k < 4; ++k) {
      o[k] = (bf16)(w0 * (float)ut[(lr4 + k) * 48 + 32 + c] +
                    w1 * (float)ut[(lr4 + k + 1) * 48 + 32 + c] +
                    w2 * (float)ut[(lr4 + k + 2) * 48 + 32 + c] + bv);
    }
    *(bf16x4*)&vv[(bn * 16 + c) * SEQLEN + l0 + lr4] = o;
  }
}

// ---------------------------------------------------------------------------
// Causal h-weighted attention v10 (frozen at its ~49.4us plateau; 6 variants
// failed to beat it). Balanced paired tiles; S^T = mfma_32x32x16(K,Q);
// zero-padded LDS h; S->A via LDS (stride 40); PV = 2x mfma_16x16x32.
// ---------------------------------------------------------------------------
__global__ __launch_bounds__(256) void attn_kernel(
    const bf16* __restrict__ qq, const bf16* __restrict__ kk,
    const bf16* __restrict__ vv, const float* __restrict__ hg,
    bf16* __restrict__ y) {
  const int nh = blockIdx.x, b = blockIdx.y;
  const int qa = blockIdx.z, qb = 63 - qa;  // paired tiles
  const int l0a = qa * 32, l0b = qb * 32;
  __shared__ __align__(16) float hs[32 + SEQLEN];  // hs[32+d]=h[d], pad=0
  __shared__ __align__(16) bf16 st[4 * 32 * SST];  // per-wave S-tile / O-redux
  const int t = threadIdx.x;
  const int n4 = (l0b + 64) >> 2;
  for (int i = t; i < n4; i += 256) {
    float4 val = {0.f, 0.f, 0.f, 0.f};
    if (i >= 8) val = ((const float4*)(hg + nh * SEQLEN))[i - 8];
    ((float4*)hs)[i] = val;
  }
  __syncthreads();

  const int w = t >> 6, lane = t & 63;
  const int l31 = lane & 31, hi = lane >> 5;
  const int row16 = lane & 15, quad = lane >> 4;
  const size_t bn = (size_t)(b * NUM_HEADS + nh);
  const bf16* qp = qq + bn * SEQLEN * 16;
  const bf16* kb = kk + bn * SEQLEN * 16;
  const bf16* vb = vv + bn * 16 * SEQLEN;

  bf16x8 zf;
#pragma unroll
  for (int j = 0; j < 8; ++j) zf[j] = (bf16)0.f;
  const f32x4 zacc4 = {0.f, 0.f, 0.f, 0.f};
  f32x16 zacc16;
#pragma unroll
  for (int j = 0; j < 16; ++j) zacc16[j] = 0.f;

  const bf16x8 qfa = *(const bf16x8*)&qp[(l0a + l31) * 16 + hi * 8];
  const bf16x8 qfb = *(const bf16x8*)&qp[(l0b + l31) * 16 + hi * 8];

  bf16* sw = &st[w * 32 * SST];

  auto run_pass = [&](const bf16x8& qf, const int l0, const int mc0,
                      f32x4& o0, f32x4& o1) {
    int mc = mc0;
    bf16x8 kf = zf, vf = zf;
    if (mc <= l0) {
      kf = *(const bf16x8*)&kb[(mc + l31) * 16 + hi * 8];
      vf = *(const bf16x8*)&vb[row16 * SEQLEN + mc + quad * 8];
    }
    for (; mc <= l0; mc += 128) {
      const int mn = mc + 128;
      bf16x8 kf2 = zf, vf2 = zf;
      if (mn <= l0) {  // prefetch next chunk
        kf2 = *(const bf16x8*)&kb[(mn + l31) * 16 + hi * 8];
        vf2 = *(const bf16x8*)&vb[row16 * SEQLEN + mn + quad * 8];
      }
      // S^T[m-local=rows][l-local=cols] = sum_ch K*Q
      f32x16 s =
          __builtin_amdgcn_mfma_f32_32x32x16_bf16(kf, qf, zacc16, 0, 0, 0);

      // h-weight; causal mask free via zero pad. reg j -> hp[3-j]
      const int d0 = 32 + (l0 - mc) + l31 - 4 * hi;
#pragma unroll
      for (int g = 0; g < 4; ++g) {
        const float* hp = &hs[d0 - 8 * g - 3];
        bf16x4 pk;
        pk[0] = (bf16)(s[4 * g + 0] * hp[3]);
        pk[1] = (bf16)(s[4 * g + 1] * hp[2]);
        pk[2] = (bf16)(s[4 * g + 2] * hp[1]);
        pk[3] = (bf16)(s[4 * g + 3] * hp[0]);
        *(bf16x4*)&sw[l31 * SST + 8 * g + 4 * hi] = pk;
      }
      asm volatile("s_waitcnt lgkmcnt(0)" ::: "memory");  // stores -> reads
      const bf16x8 sf0 = *(const bf16x8*)&sw[row16 * SST + quad * 8];
      const bf16x8 sf1 = *(const bf16x8*)&sw[(row16 + 16) * SST + quad * 8];
      o0 = __builtin_amdgcn_mfma_f32_16x16x32_bf16(sf0, vf, o0, 0, 0, 0);
      o1 = __builtin_amdgcn_mfma_f32_16x16x32_bf16(sf1, vf, o1, 0, 0, 0);
      asm volatile("" ::: "memory");  // reads before next-iter stores
      kf = kf2; vf = vf2;
    }
  };

  f32x4 o0a = zacc4, o1a = zacc4, o0b = zacc4, o1b = zacc4;
  run_pass(qfa, l0a, w * 32, o0a, o1a);
  const int j0 = ((w - qa - 1) % 4 + 4) % 4;
  run_pass(qfb, l0b, j0 * 32, o0b, o1b);

  // epilogue: two phases reusing st as 4 x (32x16 f32) reduction buffers
  float* ob = (float*)&st[w * 32 * SST];
#pragma unroll
  for (int phase = 0; phase < 2; ++phase) {
    const f32x4& p0 = phase ? o0b : o0a;
    const f32x4& p1 = phase ? o1b : o1a;
    const int lt = phase ? l0b : l0a;
    __syncthreads();
#pragma unroll
    for (int r = 0; r < 4; ++r) {
      ob[(quad * 4 + r) * 16 + row16] = p0[r];
      ob[(quad * 4 + r + 16) * 16 + row16] = p1[r];
    }
    __syncthreads();
    for (int i = t; i < 32 * 16; i += 256) {
      const int l = i >> 4, j = i & 15;
      float sum = 0.f;
#pragma unroll
      for (int ww = 0; ww < 4; ++ww)
        sum += ((const float*)&st[ww * 32 * SST])[l * 16 + j];
      y[((size_t)(b * SEQLEN + lt + l) * NUM_HEADS + nh) * 16 + j] = (bf16)sum;
    }
  }
}

// ---------------------------------------------------------------------------
extern "C" void kernel_launch(void* const* d_in, const int* in_sizes, int n_in,
                              void* d_out, int out_size, void* d_ws,
                              size_t ws_size, hipStream_t stream) {
  const float* inputs = (const float*)d_in[0];
  const float* w_in = (const float*)d_in[1];
  const float* b_in = (const float*)d_in[2];
  const float* w_sf = (const float*)d_in[3];
  const float* b_sf = (const float*)d_in[4];
  const float* hb = (const float*)d_in[5];
  const float* norm_w = (const float*)d_in[6];
  const float* w_out = (const float*)d_in[7];
  const float* b_out = (const float*)d_in[8];

  // ws plan (37.8 MB), region lifetimes:
  //   u   18.9 MB : GEMM1 out -> dead after conv_qkv; reused for
  //                 wout16 (+0, 1.2MB), y16 (+9MB, 6.3MB)
  //   v    6.3 MB : V
  //   A    6.3 MB : in16 (GEMM1 A) -> k16 (attn) -> dead
  //   B    6.3 MB : win16 (GEMM1 W, 3.5MB) -> q16 (attn)
  char* ws = (char*)d_ws;
  const size_t U_B = (size_t)M_ROWS * INNER * 2;
  const size_t V_B = (size_t)BATCH * NUM_HEADS * HEAD_CH * SEQLEN * 2;
  const size_t SLOT_B = (size_t)M_ROWS * D_MODEL * 2;
  bf16* u = (bf16*)(ws);
  bf16* wout16 = (bf16*)(ws);                    // u region, after conv
  bf16* y16 = (bf16*)(ws + (9 << 20));           // u region +9MB
  bf16* v = (bf16*)(ws + U_B);
  bf16* in16 = (bf16*)(ws + U_B + V_B);          // A
  bf16* k16 = in16;                              // A after GEMM1
  bf16* win16 = (bf16*)(ws + U_B + V_B + SLOT_B);// B
  bf16* q16 = win16;                             // B after GEMM1
  float* out = (float*)d_out;

  const int n4_in = M_ROWS * D_MODEL / 4;
  const int n4_win = INNER * D_MODEL / 4;
  const int n4_wout = D_MODEL * D_MODEL / 4;
  hipLaunchKernelGGL(cvt2_f32_bf16, dim3((n4_in + n4_win + 255) / 256),
                     dim3(256), 0, stream, inputs, in16, n4_in, w_in, win16,
                     n4_win);

  // gemm1: 128x128 m97 geometry + XCD swizzle (576 blocks, %8==0)
  hipLaunchKernelGGL((gemm_bt<128, 128, 64, INNER, bf16>), dim3(32, 18),
                     dim3(256), 0, stream, in16, win16, b_in, u, 768);
  hipLaunchKernelGGL(conv_qkv, dim3(48, 2, 16), dim3(256), 0, stream, u, w_sf,
                     b_sf, q16, k16, v);
  // u dead now: stage w_out*nw into its head
  hipLaunchKernelGGL(cvt_wout_nw, dim3((n4_wout + 255) / 256), dim3(256), 0,
                     stream, w_out, norm_w, wout16, n4_wout);
  hipLaunchKernelGGL(attn_kernel, dim3(48, 2, 32), dim3(256), 0, stream, q16,
                     k16, v, hb, y16);
  // gemm2 + fused RMSNorm + skip, 128x64 tile (384 blocks, %8==0)
  hipLaunchKernelGGL(gemm_rms, dim3(32, 12), dim3(256), 0, stream, y16, wout16,
                     b_out, inputs, out);
}

// Round 10
// 185.916 us; speedup vs baseline: 1.0200x; 1.0200x over previous
//
#include <hip/hip_runtime.h>
#include <hip/hip_bf16.h>
#include <stdint.h>

typedef __bf16 bf16;
typedef __bf16 bf16x4 __attribute__((ext_vector_type(4)));
typedef __bf16 bf16x8 __attribute__((ext_vector_type(8)));
typedef float f32x4 __attribute__((ext_vector_type(4)));
typedef float f32x16 __attribute__((ext_vector_type(16)));

#define D_MODEL 768
#define NUM_HEADS 48
#define HEAD_CH 16
#define INNER 2304
#define BATCH 2
#define SEQLEN 2048
#define M_ROWS (BATCH * SEQLEN)
#define EPSF 1e-6f
// S-tile stride (bf16). MUST be 0 mod 8 (16B row alignment for ds_read_b128).
#define SST 40

// async global->LDS, 16B per lane. LDS dest must be wave-uniform base + lane*16.
__device__ inline void gload_lds16(const void* g, void* l) {
  __builtin_amdgcn_global_load_lds((__attribute__((address_space(1))) void*)(g),
                                   (__attribute__((address_space(3))) void*)(l),
                                   16, 0, 0);
}

// XCD-aware bijective block remap (requires nwg % 8 == 0).
__device__ inline void xcd_swz(int& bx, int& by) {
  const int nx = gridDim.x;
  const int f = bx + nx * by;
  const int q = (nx * gridDim.y) >> 3;
  const int s = (f & 7) * q + (f >> 3);
  bx = s % nx;
  by = s / nx;
}

// ---------------------------------------------------------------------------
// fused dual f32 -> bf16 convert (two independent tensors, one launch)
// ---------------------------------------------------------------------------
__global__ __launch_bounds__(256) void cvt2_f32_bf16(
    const float* __restrict__ a, bf16* __restrict__ da, int na4,
    const float* __restrict__ b, bf16* __restrict__ db, int nb4) {
  int j = blockIdx.x * 256 + threadIdx.x;
  const float* s;
  bf16* d;
  if (j < na4) {
    s = a; d = da;
  } else {
    j -= na4;
    if (j >= nb4) return;
    s = b; d = db;
  }
  const float4 v = ((const float4*)s)[j];
  bf16x4 o;
  o[0] = (bf16)v.x; o[1] = (bf16)v.y; o[2] = (bf16)v.z; o[3] = (bf16)v.w;
  ((bf16x4*)d)[j] = o;
}

// ---------------------------------------------------------------------------
// w_out * norm_w  f32 -> bf16 (norm_w folded along the contraction dim d)
// ---------------------------------------------------------------------------
__global__ __launch_bounds__(256) void cvt_wout_nw(
    const float* __restrict__ src, const float* __restrict__ nw,
    bf16* __restrict__ dst, int n4) {
  const int i = blockIdx.x * 256 + threadIdx.x;
  if (i < n4) {
    const int d0 = (i * 4) % D_MODEL;
    const float4 v = ((const float4*)src)[i];
    const float4 nv = *(const float4*)&nw[d0];
    bf16x4 o;
    o[0] = (bf16)(v.x * nv.x); o[1] = (bf16)(v.y * nv.y);
    o[2] = (bf16)(v.z * nv.z); o[3] = (bf16)(v.w * nv.w);
    ((bf16x4*)dst)[i] = o;
  }
}

// ---------------------------------------------------------------------------
// GEMM1: C[m,n] = sum_k A[m,k]*W[n,k] + bias[n]; m97 pattern, 128x128, BK=64.
// ---------------------------------------------------------------------------
template <int TM, int TN, int BK, int NCOLS, typename CT>
__global__ __launch_bounds__(256) void gemm_bt(
    const bf16* __restrict__ A, const bf16* __restrict__ W,
    const float* __restrict__ bias, CT* __restrict__ C, int K) {
  constexpr int MI = TM / 32;
  constexpr int NI = TN / 32;
  constexpr int KK = BK / 32;
  __shared__ __align__(16) bf16 As[TM * BK];
  __shared__ __align__(16) bf16 Bs[TN * BK];
  const int t = threadIdx.x;
  const int lane = t & 63, w = t >> 6;
  const int wm = (w >> 1) * (TM / 2), wn = (w & 1) * (TN / 2);
  const int row16 = lane & 15, quad = lane >> 4;
  int bx = blockIdx.x, by = blockIdx.y;
  xcd_swz(bx, by);
  const int m0 = bx * TM, n0 = by * TN;

  f32x4 zero4 = {0.f, 0.f, 0.f, 0.f};
  f32x4 acc[MI][NI];
#pragma unroll
  for (int mi = 0; mi < MI; ++mi)
#pragma unroll
    for (int ni = 0; ni < NI; ++ni) acc[mi][ni] = zero4;

  const int arow = t >> 2;        // 0..63
  const int acol = (t & 3) * 8;   // 0..24
  const bf16* Ab = A + (size_t)m0 * K;
  const bf16* Wb = W + (size_t)n0 * K;

  for (int kt = 0; kt < K; kt += BK) {
#pragma unroll
    for (int kk0 = 0; kk0 < KK; ++kk0) {
#pragma unroll
      for (int rh = 0; rh < TM / 64; ++rh)
        gload_lds16(Ab + (size_t)(rh * 64 + arow) * K + kt + kk0 * 32 + acol,
                    As + kk0 * (TM * 32) + rh * 2048 + t * 8);
#pragma unroll
      for (int rh = 0; rh < TN / 64; ++rh)
        gload_lds16(Wb + (size_t)(rh * 64 + arow) * K + kt + kk0 * 32 + acol,
                    Bs + kk0 * (TN * 32) + rh * 2048 + t * 8);
    }
    __syncthreads();

    bf16x8 af[MI][KK], wf[NI][KK];
#pragma unroll
    for (int kk0 = 0; kk0 < KK; ++kk0) {
#pragma unroll
      for (int mi = 0; mi < MI; ++mi)
        af[mi][kk0] = *(const bf16x8*)&As[kk0 * (TM * 32) +
                                          (wm + mi * 16 + row16) * 32 +
                                          quad * 8];
#pragma unroll
      for (int ni = 0; ni < NI; ++ni)
        wf[ni][kk0] = *(const bf16x8*)&Bs[kk0 * (TN * 32) +
                                          (wn + ni * 16 + row16) * 32 +
                                          quad * 8];
    }
#pragma unroll
    for (int kk0 = 0; kk0 < KK; ++kk0)
#pragma unroll
      for (int mi = 0; mi < MI; ++mi)
#pragma unroll
        for (int ni = 0; ni < NI; ++ni)
          acc[mi][ni] = __builtin_amdgcn_mfma_f32_16x16x32_bf16(
              af[mi][kk0], wf[ni][kk0], acc[mi][ni], 0, 0, 0);
    __syncthreads();
  }

#pragma unroll
  for (int mi = 0; mi < MI; ++mi) {
#pragma unroll
    for (int ni = 0; ni < NI; ++ni) {
      const int col = n0 + wn + ni * 16 + row16;
      const float bv = bias[col];
#pragma unroll
      for (int r = 0; r < 4; ++r) {
        const int row = m0 + wm + mi * 16 + quad * 4 + r;
        C[(size_t)row * NCOLS + col] = (CT)(acc[mi][ni][r] + bv);
      }
    }
  }
}

// ---------------------------------------------------------------------------
// GEMM2 + fused RMSNorm (r8-exact, 64x64): out = r[m]*sum y*W' + b + skip.
// ---------------------------------------------------------------------------
__global__ __launch_bounds__(256) void gemm_rms(
    const bf16* __restrict__ A, const bf16* __restrict__ W,
    const float* __restrict__ bias, const float* __restrict__ skip,
    float* __restrict__ C) {
  constexpr int TM = 64, TN = 64, BK = 64, K = D_MODEL;
  constexpr int MI = 2, NI = 2, KK = 2;
  __shared__ __align__(16) bf16 As[TM * BK];
  __shared__ __align__(16) bf16 Bs[TN * BK];
  __shared__ float rs[TM];
  const int t = threadIdx.x;
  const int lane = t & 63, w = t >> 6;
  const int wm = (w >> 1) * 32, wn = (w & 1) * 32;
  const int row16 = lane & 15, quad = lane >> 4;
  int bx = blockIdx.x, by = blockIdx.y;
  xcd_swz(bx, by);
  const int m0 = bx * TM, n0 = by * TN;

  f32x4 zero4 = {0.f, 0.f, 0.f, 0.f};
  f32x4 acc[MI][NI];
#pragma unroll
  for (int mi = 0; mi < MI; ++mi)
#pragma unroll
    for (int ni = 0; ni < NI; ++ni) acc[mi][ni] = zero4;

  const int arow = t >> 2;
  const int acol = (t & 3) * 8;
  const bf16* Ab = A + (size_t)m0 * K;
  const bf16* Wb = W + (size_t)n0 * K;
  float ssq = 0.f;

  for (int kt = 0; kt < K; kt += BK) {
#pragma unroll
    for (int kk0 = 0; kk0 < KK; ++kk0) {
      gload_lds16(Ab + (size_t)arow * K + kt + kk0 * 32 + acol,
                  As + kk0 * (TM * 32) + t * 8);
      gload_lds16(Wb + (size_t)arow * K + kt + kk0 * 32 + acol,
                  Bs + kk0 * (TN * 32) + t * 8);
    }
    __syncthreads();

    bf16x8 af[MI][KK], wf[NI][KK];
#pragma unroll
    for (int kk0 = 0; kk0 < KK; ++kk0) {
#pragma unroll
      for (int mi = 0; mi < MI; ++mi)
        af[mi][kk0] = *(const bf16x8*)&As[kk0 * (TM * 32) +
                                          (wm + mi * 16 + row16) * 32 +
                                          quad * 8];
#pragma unroll
      for (int ni = 0; ni < NI; ++ni)
        wf[ni][kk0] = *(const bf16x8*)&Bs[kk0 * (TN * 32) +
                                          (wn + ni * 16 + row16) * 32 +
                                          quad * 8];
    }
    // ssq partial: thread t covers row t>>2, cols (t&3)*8..+8 of both kk0
#pragma unroll
    for (int kk0 = 0; kk0 < KK; ++kk0) {
      const bf16x8 q =
          *(const bf16x8*)&As[kk0 * (TM * 32) + (t >> 2) * 32 + (t & 3) * 8];
#pragma unroll
      for (int jj = 0; jj < 8; ++jj) {
        const float f = (float)q[jj];
        ssq += f * f;
      }
    }
#pragma unroll
    for (int kk0 = 0; kk0 < KK; ++kk0)
#pragma unroll
      for (int mi = 0; mi < MI; ++mi)
#pragma unroll
        for (int ni = 0; ni < NI; ++ni)
          acc[mi][ni] = __builtin_amdgcn_mfma_f32_16x16x32_bf16(
              af[mi][kk0], wf[ni][kk0], acc[mi][ni], 0, 0, 0);
    __syncthreads();
  }

  // reduce ssq (4 threads per row) -> rs[row]
  float* ssr = (float*)As;  // As dead after loop
  ssr[t] = ssq;
  __syncthreads();
  if (t < TM) {
    const float s4 = ssr[4 * t] + ssr[4 * t + 1] + ssr[4 * t + 2] + ssr[4 * t + 3];
    rs[t] = rsqrtf(s4 * (1.f / (float)D_MODEL) + EPSF);
  }
  __syncthreads();

#pragma unroll
  for (int mi = 0; mi < MI; ++mi) {
#pragma unroll
    for (int ni = 0; ni < NI; ++ni) {
      const int col = n0 + wn + ni * 16 + row16;
      const float bv = bias[col];
#pragma unroll
      for (int r = 0; r < 4; ++r) {
        const int rowl = wm + mi * 16 + quad * 4 + r;
        const int row = m0 + rowl;
        C[(size_t)row * D_MODEL + col] =
            acc[mi][ni][r] * rs[rowl] + bv + skip[(size_t)row * D_MODEL + col];
      }
    }
  }
}

// ---------------------------------------------------------------------------
// Q+K+V causal width-3 conv from u (r8-exact scalar version):
//   ch 0..15  -> Q (B,N,L,16);  16..31 -> K (B,N,L,16);  32..47 -> V (B,N,16,L)
// ---------------------------------------------------------------------------
__global__ __launch_bounds__(256) void conv_qkv(
    const bf16* __restrict__ u, const float* __restrict__ w_sf,
    const float* __restrict__ b_sf, bf16* __restrict__ qq,
    bf16* __restrict__ kk, bf16* __restrict__ vv) {
  const int nh = blockIdx.x, b = blockIdx.y, lc = blockIdx.z;
  const int l0 = lc * 128;
  __shared__ __align__(8) bf16 ut[130 * 48];
  const int t = threadIdx.x;
  for (int i = t; i < 130 * 12; i += 256) {
    const int lr = i / 12, qd = i % 12;
    const int l = l0 - 2 + lr;
    uint2 val;
    val.x = 0u; val.y = 0u;
    if (l >= 0)
      val = *(const uint2*)&u[(size_t)(b * SEQLEN + l) * INNER + nh * 48 + qd * 4];
    *(uint2*)&ut[lr * 48 + qd * 4] = val;
  }
  __syncthreads();
  const size_t bn = (size_t)(b * NUM_HEADS + nh);
#pragma unroll
  for (int s = 0; s < 2; ++s) {
    bf16* dst = (s == 0) ? qq : kk;
    const int cb = s * 16;
    for (int i = t; i < 128 * 16; i += 256) {
      const int c = i & 15, lr = i >> 4;
      const int e = nh * 48 + cb + c;
      const float val = w_sf[e * 3 + 0] * (float)ut[lr * 48 + cb + c] +
                        w_sf[e * 3 + 1] * (float)ut[(lr + 1) * 48 + cb + c] +
                        w_sf[e * 3 + 2] * (float)ut[(lr + 2) * 48 + cb + c] +
                        b_sf[e];
      dst[(bn * SEQLEN + l0 + lr) * 16 + c] = (bf16)val;
    }
  }
  for (int i = t; i < 128 * 16; i += 256) {
    const int lr = i & 127, c = i >> 7;
    const int e = nh * 48 + 32 + c;
    const float val = w_sf[e * 3 + 0] * (float)ut[lr * 48 + 32 + c] +
                      w_sf[e * 3 + 1] * (float)ut[(lr + 1) * 48 + 32 + c] +
                      w_sf[e * 3 + 2] * (float)ut[(lr + 2) * 48 + 32 + c] +
                      b_sf[e];
    vv[(bn * 16 + c) * SEQLEN + l0 + lr] = (bf16)val;
  }
}

// ---------------------------------------------------------------------------
// Causal h-weighted attention v15: v10 + double-buffered S-tile pipeline.
// Per iteration: QK_{i+1} issues BEFORE the lgkmcnt that gates PV_i, and the
// stores of S_{i+1} happen AFTER PV_i into the other buffer. The LDS
// store-drain (~120+ cyc, previously serial in every iteration) moves off
// the critical path: stores have a full iteration to complete.
// ---------------------------------------------------------------------------
__global__ __launch_bounds__(256) void attn_kernel(
    const bf16* __restrict__ qq, const bf16* __restrict__ kk,
    const bf16* __restrict__ vv, const float* __restrict__ hg,
    bf16* __restrict__ y) {
  const int nh = blockIdx.x, b = blockIdx.y;
  const int qa = blockIdx.z, qb = 63 - qa;  // paired tiles
  const int l0a = qa * 32, l0b = qb * 32;
  __shared__ __align__(16) float hs[32 + SEQLEN];  // hs[32+d]=h[d], pad=0
  __shared__ __align__(16) bf16 st[8 * 32 * SST];  // 2 S-bufs per wave
  const int t = threadIdx.x;
  const int n4 = (l0b + 64) >> 2;
  for (int i = t; i < n4; i += 256) {
    float4 val = {0.f, 0.f, 0.f, 0.f};
    if (i >= 8) val = ((const float4*)(hg + nh * SEQLEN))[i - 8];
    ((float4*)hs)[i] = val;
  }
  __syncthreads();

  const int w = t >> 6, lane = t & 63;
  const int l31 = lane & 31, hi = lane >> 5;
  const int row16 = lane & 15, quad = lane >> 4;
  const size_t bn = (size_t)(b * NUM_HEADS + nh);
  const bf16* qp = qq + bn * SEQLEN * 16;
  const bf16* kb = kk + bn * SEQLEN * 16;
  const bf16* vb = vv + bn * 16 * SEQLEN;

  bf16x8 zf;
#pragma unroll
  for (int j = 0; j < 8; ++j) zf[j] = (bf16)0.f;
  const f32x4 zacc4 = {0.f, 0.f, 0.f, 0.f};
  f32x16 zacc16;
#pragma unroll
  for (int j = 0; j < 16; ++j) zacc16[j] = 0.f;

  const bf16x8 qfa = *(const bf16x8*)&qp[(l0a + l31) * 16 + hi * 8];
  const bf16x8 qfb = *(const bf16x8*)&qp[(l0b + l31) * 16 + hi * 8];

  bf16* sw0 = &st[(size_t)w * 2 * 32 * SST];
  bf16* sw1 = sw0 + 32 * SST;

  auto ldK = [&](int mc) { return *(const bf16x8*)&kb[(mc + l31) * 16 + hi * 8]; };
  auto ldV = [&](int mc) { return *(const bf16x8*)&vb[row16 * SEQLEN + mc + quad * 8]; };
  // weight S by h and store row l31 of the P-tile into buf
  auto wstore = [&](const f32x16& s, const int delta, bf16* buf) {
    const int d0 = 32 + delta + l31 - 4 * hi;
#pragma unroll
    for (int g = 0; g < 4; ++g) {
      const float* hp = &hs[d0 - 8 * g - 3];
      bf16x4 pk;
      pk[0] = (bf16)(s[4 * g + 0] * hp[3]);
      pk[1] = (bf16)(s[4 * g + 1] * hp[2]);
      pk[2] = (bf16)(s[4 * g + 2] * hp[1]);
      pk[3] = (bf16)(s[4 * g + 3] * hp[0]);
      *(bf16x4*)&buf[l31 * SST + 8 * g + 4 * hi] = pk;
    }
  };
  auto pv = [&](const bf16* buf, const bf16x8 vf, f32x4& o0, f32x4& o1) {
    const bf16x8 sf0 = *(const bf16x8*)&buf[row16 * SST + quad * 8];
    const bf16x8 sf1 = *(const bf16x8*)&buf[(row16 + 16) * SST + quad * 8];
    o0 = __builtin_amdgcn_mfma_f32_16x16x32_bf16(sf0, vf, o0, 0, 0, 0);
    o1 = __builtin_amdgcn_mfma_f32_16x16x32_bf16(sf1, vf, o1, 0, 0, 0);
  };

  auto run_pass = [&](const bf16x8& qf, const int l0, const int mc0,
                      f32x4& o0, f32x4& o1) {
    int mc = mc0;
    if (mc > l0) return;
    // prologue: chunk 0 -> QK -> store buf0; prefetch chunk 1
    bf16x8 k0 = ldK(mc);
    bf16x8 vf0 = ldV(mc);
    f32x16 s0 = __builtin_amdgcn_mfma_f32_32x32x16_bf16(k0, qf, zacc16, 0, 0, 0);
    bf16x8 kf1 = zf, vf1 = zf;
    if (mc + 128 <= l0) { kf1 = ldK(mc + 128); vf1 = ldV(mc + 128); }
    wstore(s0, l0 - mc, sw0);
    int p = 0;  // buffer holding the current (un-consumed) chunk
    for (; mc + 128 <= l0; mc += 128) {
      bf16x8 kf2 = zf, vf2 = zf;
      if (mc + 256 <= l0) { kf2 = ldK(mc + 256); vf2 = ldV(mc + 256); }
      // QK for chunk i+1: independent MFMA, overlaps the store-drain below
      f32x16 s2 =
          __builtin_amdgcn_mfma_f32_32x32x16_bf16(kf1, qf, zacc16, 0, 0, 0);
      asm volatile("s_waitcnt lgkmcnt(0)" ::: "memory");  // stores of buf[p]
      pv(p ? sw1 : sw0, vf0, o0, o1);                     // PV chunk i
      wstore(s2, l0 - (mc + 128), p ? sw0 : sw1);         // store chunk i+1
      p ^= 1;
      kf1 = kf2; vf0 = vf1; vf1 = vf2;
    }
    // epilogue: last chunk sits in buf[p]
    asm volatile("s_waitcnt lgkmcnt(0)" ::: "memory");
    pv(p ? sw1 : sw0, vf0, o0, o1);
    asm volatile("" ::: "memory");
  };

  f32x4 o0a = zacc4, o1a = zacc4, o0b = zacc4, o1b = zacc4;
  run_pass(qfa, l0a, w * 32, o0a, o1a);
  const int j0 = ((w - qa - 1) % 4 + 4) % 4;
  run_pass(qfb, l0b, j0 * 32, o0b, o1b);

  // epilogue: two phases reusing st as 4 x (32x16 f32) reduction buffers
  float* ob = (float*)&st[(size_t)w * 2 * 32 * SST];
#pragma unroll
  for (int phase = 0; phase < 2; ++phase) {
    const f32x4& p0 = phase ? o0b : o0a;
    const f32x4& p1 = phase ? o1b : o1a;
    const int lt = phase ? l0b : l0a;
    __syncthreads();
#pragma unroll
    for (int r = 0; r < 4; ++r) {
      ob[(quad * 4 + r) * 16 + row16] = p0[r];
      ob[(quad * 4 + r + 16) * 16 + row16] = p1[r];
    }
    __syncthreads();
    for (int i = t; i < 32 * 16; i += 256) {
      const int l = i >> 4, j = i & 15;
      float sum = 0.f;
#pragma unroll
      for (int ww = 0; ww < 4; ++ww)
        sum += ((const float*)&st[(size_t)ww * 2 * 32 * SST])[l * 16 + j];
      y[((size_t)(b * SEQLEN + lt + l) * NUM_HEADS + nh) * 16 + j] = (bf16)sum;
    }
  }
}

// ---------------------------------------------------------------------------
extern "C" void kernel_launch(void* const* d_in, const int* in_sizes, int n_in,
                              void* d_out, int out_size, void* d_ws,
                              size_t ws_size, hipStream_t stream) {
  const float* inputs = (const float*)d_in[0];
  const float* w_in = (const float*)d_in[1];
  const float* b_in = (const float*)d_in[2];
  const float* w_sf = (const float*)d_in[3];
  const float* b_sf = (const float*)d_in[4];
  const float* hb = (const float*)d_in[5];
  const float* norm_w = (const float*)d_in[6];
  const float* w_out = (const float*)d_in[7];
  const float* b_out = (const float*)d_in[8];

  // ws plan (37.8 MB), region lifetimes:
  //   u   18.9 MB : GEMM1 out -> dead after conv_qkv; reused for
  //                 wout16 (+0, 1.2MB), y16 (+9MB, 6.3MB)
  //   v    6.3 MB : V
  //   A    6.3 MB : in16 (GEMM1 A) -> k16 (attn) -> dead
  //   B    6.3 MB : win16 (GEMM1 W, 3.5MB) -> q16 (attn)
  char* ws = (char*)d_ws;
  const size_t U_B = (size_t)M_ROWS * INNER * 2;
  const size_t V_B = (size_t)BATCH * NUM_HEADS * HEAD_CH * SEQLEN * 2;
  const size_t SLOT_B = (size_t)M_ROWS * D_MODEL * 2;
  bf16* u = (bf16*)(ws);
  bf16* wout16 = (bf16*)(ws);                    // u region, after conv
  bf16* y16 = (bf16*)(ws + (9 << 20));           // u region +9MB
  bf16* v = (bf16*)(ws + U_B);
  bf16* in16 = (bf16*)(ws + U_B + V_B);          // A
  bf16* k16 = in16;                              // A after GEMM1
  bf16* win16 = (bf16*)(ws + U_B + V_B + SLOT_B);// B
  bf16* q16 = win16;                             // B after GEMM1
  float* out = (float*)d_out;

  const int n4_in = M_ROWS * D_MODEL / 4;
  const int n4_win = INNER * D_MODEL / 4;
  const int n4_wout = D_MODEL * D_MODEL / 4;
  hipLaunchKernelGGL(cvt2_f32_bf16, dim3((n4_in + n4_win + 255) / 256),
                     dim3(256), 0, stream, inputs, in16, n4_in, w_in, win16,
                     n4_win);

  // gemm1: 128x128 m97 geometry + XCD swizzle (576 blocks, %8==0)
  hipLaunchKernelGGL((gemm_bt<128, 128, 64, INNER, bf16>), dim3(32, 18),
                     dim3(256), 0, stream, in16, win16, b_in, u, 768);
  hipLaunchKernelGGL(conv_qkv, dim3(48, 2, 16), dim3(256), 0, stream, u, w_sf,
                     b_sf, q16, k16, v);
  // u dead now: stage w_out*nw into its head
  hipLaunchKernelGGL(cvt_wout_nw, dim3((n4_wout + 255) / 256), dim3(256), 0,
                     stream, w_out, norm_w, wout16, n4_wout);
  hipLaunchKernelGGL(attn_kernel, dim3(48, 2, 32), dim3(256), 0, stream, q16,
                     k16, v, hb, y16);
  // gemm2 + fused RMSNorm + skip (768 blocks, %8==0)
  hipLaunchKernelGGL(gemm_rms, dim3(64, 12), dim3(256), 0, stream, y16, wout16,
                     b_out, inputs, out);
}

// Round 11
// 185.008 us; speedup vs baseline: 1.0250x; 1.0049x over previous
//
#include <hip/hip_runtime.h>
#include <hip/hip_bf16.h>
#include <stdint.h>

typedef __bf16 bf16;
typedef __bf16 bf16x4 __attribute__((ext_vector_type(4)));
typedef __bf16 bf16x8 __attribute__((ext_vector_type(8)));
typedef float f32x4 __attribute__((ext_vector_type(4)));
typedef float f32x16 __attribute__((ext_vector_type(16)));

#define D_MODEL 768
#define NUM_HEADS 48
#define HEAD_CH 16
#define INNER 2304
#define BATCH 2
#define SEQLEN 2048
#define M_ROWS (BATCH * SEQLEN)
#define EPSF 1e-6f
// S-tile stride (bf16). MUST be 0 mod 8 (16B row alignment for ds_read_b128).
#define SST 40
#define N4WOUT (D_MODEL * D_MODEL / 4)

// async global->LDS, 16B per lane. LDS dest must be wave-uniform base + lane*16.
__device__ inline void gload_lds16(const void* g, void* l) {
  __builtin_amdgcn_global_load_lds((__attribute__((address_space(1))) void*)(g),
                                   (__attribute__((address_space(3))) void*)(l),
                                   16, 0, 0);
}

// XCD-aware bijective block remap (requires nwg % 8 == 0).
__device__ inline void xcd_swz(int& bx, int& by) {
  const int nx = gridDim.x;
  const int f = bx + nx * by;
  const int q = (nx * gridDim.y) >> 3;
  const int s = (f & 7) * q + (f >> 3);
  bx = s % nx;
  by = s / nx;
}

// ---------------------------------------------------------------------------
// fused dual f32 -> bf16 convert (two independent tensors, one launch)
// ---------------------------------------------------------------------------
__global__ __launch_bounds__(256) void cvt2_f32_bf16(
    const float* __restrict__ a, bf16* __restrict__ da, int na4,
    const float* __restrict__ b, bf16* __restrict__ db, int nb4) {
  int j = blockIdx.x * 256 + threadIdx.x;
  const float* s;
  bf16* d;
  if (j < na4) {
    s = a; d = da;
  } else {
    j -= na4;
    if (j >= nb4) return;
    s = b; d = db;
  }
  const float4 v = ((const float4*)s)[j];
  bf16x4 o;
  o[0] = (bf16)v.x; o[1] = (bf16)v.y; o[2] = (bf16)v.z; o[3] = (bf16)v.w;
  ((bf16x4*)d)[j] = o;
}

// ---------------------------------------------------------------------------
// GEMM1: C[m,n] = sum_k A[m,k]*W[n,k] + bias[n]; m97 pattern, 128x128, BK=64.
// ---------------------------------------------------------------------------
template <int TM, int TN, int BK, int NCOLS, typename CT>
__global__ __launch_bounds__(256) void gemm_bt(
    const bf16* __restrict__ A, const bf16* __restrict__ W,
    const float* __restrict__ bias, CT* __restrict__ C, int K) {
  constexpr int MI = TM / 32;
  constexpr int NI = TN / 32;
  constexpr int KK = BK / 32;
  __shared__ __align__(16) bf16 As[TM * BK];
  __shared__ __align__(16) bf16 Bs[TN * BK];
  const int t = threadIdx.x;
  const int lane = t & 63, w = t >> 6;
  const int wm = (w >> 1) * (TM / 2), wn = (w & 1) * (TN / 2);
  const int row16 = lane & 15, quad = lane >> 4;
  int bx = blockIdx.x, by = blockIdx.y;
  xcd_swz(bx, by);
  const int m0 = bx * TM, n0 = by * TN;

  f32x4 zero4 = {0.f, 0.f, 0.f, 0.f};
  f32x4 acc[MI][NI];
#pragma unroll
  for (int mi = 0; mi < MI; ++mi)
#pragma unroll
    for (int ni = 0; ni < NI; ++ni) acc[mi][ni] = zero4;

  const int arow = t >> 2;        // 0..63
  const int acol = (t & 3) * 8;   // 0..24
  const bf16* Ab = A + (size_t)m0 * K;
  const bf16* Wb = W + (size_t)n0 * K;

  for (int kt = 0; kt < K; kt += BK) {
#pragma unroll
    for (int kk0 = 0; kk0 < KK; ++kk0) {
#pragma unroll
      for (int rh = 0; rh < TM / 64; ++rh)
        gload_lds16(Ab + (size_t)(rh * 64 + arow) * K + kt + kk0 * 32 + acol,
                    As + kk0 * (TM * 32) + rh * 2048 + t * 8);
#pragma unroll
      for (int rh = 0; rh < TN / 64; ++rh)
        gload_lds16(Wb + (size_t)(rh * 64 + arow) * K + kt + kk0 * 32 + acol,
                    Bs + kk0 * (TN * 32) + rh * 2048 + t * 8);
    }
    __syncthreads();

    bf16x8 af[MI][KK], wf[NI][KK];
#pragma unroll
    for (int kk0 = 0; kk0 < KK; ++kk0) {
#pragma unroll
      for (int mi = 0; mi < MI; ++mi)
        af[mi][kk0] = *(const bf16x8*)&As[kk0 * (TM * 32) +
                                          (wm + mi * 16 + row16) * 32 +
                                          quad * 8];
#pragma unroll
      for (int ni = 0; ni < NI; ++ni)
        wf[ni][kk0] = *(const bf16x8*)&Bs[kk0 * (TN * 32) +
                                          (wn + ni * 16 + row16) * 32 +
                                          quad * 8];
    }
#pragma unroll
    for (int kk0 = 0; kk0 < KK; ++kk0)
#pragma unroll
      for (int mi = 0; mi < MI; ++mi)
#pragma unroll
        for (int ni = 0; ni < NI; ++ni)
          acc[mi][ni] = __builtin_amdgcn_mfma_f32_16x16x32_bf16(
              af[mi][kk0], wf[ni][kk0], acc[mi][ni], 0, 0, 0);
    __syncthreads();
  }

#pragma unroll
  for (int mi = 0; mi < MI; ++mi) {
#pragma unroll
    for (int ni = 0; ni < NI; ++ni) {
      const int col = n0 + wn + ni * 16 + row16;
      const float bv = bias[col];
#pragma unroll
      for (int r = 0; r < 4; ++r) {
        const int row = m0 + wm + mi * 16 + quad * 4 + r;
        C[(size_t)row * NCOLS + col] = (CT)(acc[mi][ni][r] + bv);
      }
    }
  }
}

// ---------------------------------------------------------------------------
// GEMM2 + fused RMSNorm, 64x64 tile, BK=128 (6 K-iters vs 12: half the
// barriers on a barrier-bound short-K GEMM). out = r[m]*sum y*W' + b + skip.
// ---------------------------------------------------------------------------
__global__ __launch_bounds__(256) void gemm_rms(
    const bf16* __restrict__ A, const bf16* __restrict__ W,
    const float* __restrict__ bias, const float* __restrict__ skip,
    float* __restrict__ C) {
  constexpr int TM = 64, TN = 64, BK = 128, K = D_MODEL;
  constexpr int MI = 2, NI = 2, KK = 4;
  __shared__ __align__(16) bf16 As[TM * BK];  // 16 KB, [kk0][64][32]
  __shared__ __align__(16) bf16 Bs[TN * BK];  // 16 KB
  __shared__ float rs[TM];
  const int t = threadIdx.x;
  const int lane = t & 63, w = t >> 6;
  const int wm = (w >> 1) * 32, wn = (w & 1) * 32;
  const int row16 = lane & 15, quad = lane >> 4;
  int bx = blockIdx.x, by = blockIdx.y;
  xcd_swz(bx, by);
  const int m0 = bx * TM, n0 = by * TN;

  f32x4 zero4 = {0.f, 0.f, 0.f, 0.f};
  f32x4 acc[MI][NI];
#pragma unroll
  for (int mi = 0; mi < MI; ++mi)
#pragma unroll
    for (int ni = 0; ni < NI; ++ni) acc[mi][ni] = zero4;

  const int arow = t >> 2;
  const int acol = (t & 3) * 8;
  const bf16* Ab = A + (size_t)m0 * K;
  const bf16* Wb = W + (size_t)n0 * K;
  float ssq = 0.f;

  for (int kt = 0; kt < K; kt += BK) {
#pragma unroll
    for (int kk0 = 0; kk0 < KK; ++kk0) {
      gload_lds16(Ab + (size_t)arow * K + kt + kk0 * 32 + acol,
                  As + kk0 * (TM * 32) + t * 8);
      gload_lds16(Wb + (size_t)arow * K + kt + kk0 * 32 + acol,
                  Bs + kk0 * (TN * 32) + t * 8);
    }
    __syncthreads();

    bf16x8 af[MI][KK], wf[NI][KK];
#pragma unroll
    for (int kk0 = 0; kk0 < KK; ++kk0) {
#pragma unroll
      for (int mi = 0; mi < MI; ++mi)
        af[mi][kk0] = *(const bf16x8*)&As[kk0 * (TM * 32) +
                                          (wm + mi * 16 + row16) * 32 +
                                          quad * 8];
#pragma unroll
      for (int ni = 0; ni < NI; ++ni)
        wf[ni][kk0] = *(const bf16x8*)&Bs[kk0 * (TN * 32) +
                                          (wn + ni * 16 + row16) * 32 +
                                          quad * 8];
    }
    // ssq partial: exactly the elements this thread DMA'd
#pragma unroll
    for (int kk0 = 0; kk0 < KK; ++kk0) {
      const bf16x8 q = *(const bf16x8*)&As[kk0 * (TM * 32) + t * 8];
#pragma unroll
      for (int jj = 0; jj < 8; ++jj) {
        const float f = (float)q[jj];
        ssq += f * f;
      }
    }
#pragma unroll
    for (int kk0 = 0; kk0 < KK; ++kk0)
#pragma unroll
      for (int mi = 0; mi < MI; ++mi)
#pragma unroll
        for (int ni = 0; ni < NI; ++ni)
          acc[mi][ni] = __builtin_amdgcn_mfma_f32_16x16x32_bf16(
              af[mi][kk0], wf[ni][kk0], acc[mi][ni], 0, 0, 0);
    __syncthreads();
  }

  // reduce ssq (4 threads per row) -> rs[row]
  float* ssr = (float*)As;  // As dead after loop
  ssr[t] = ssq;
  __syncthreads();
  if (t < TM) {
    const float s4 = ssr[4 * t] + ssr[4 * t + 1] + ssr[4 * t + 2] + ssr[4 * t + 3];
    rs[t] = rsqrtf(s4 * (1.f / (float)D_MODEL) + EPSF);
  }
  __syncthreads();

#pragma unroll
  for (int mi = 0; mi < MI; ++mi) {
#pragma unroll
    for (int ni = 0; ni < NI; ++ni) {
      const int col = n0 + wn + ni * 16 + row16;
      const float bv = bias[col];
#pragma unroll
      for (int r = 0; r < 4; ++r) {
        const int rowl = wm + mi * 16 + quad * 4 + r;
        const int row = m0 + rowl;
        C[(size_t)row * D_MODEL + col] =
            acc[mi][ni][r] * rs[rowl] + bv + skip[(size_t)row * D_MODEL + col];
      }
    }
  }
}

// ---------------------------------------------------------------------------
// Q+K+V causal width-3 conv from u (r8-exact scalar version):
//   ch 0..15  -> Q (B,N,L,16);  16..31 -> K (B,N,L,16);  32..47 -> V (B,N,16,L)
// ---------------------------------------------------------------------------
__global__ __launch_bounds__(256) void conv_qkv(
    const bf16* __restrict__ u, const float* __restrict__ w_sf,
    const float* __restrict__ b_sf, bf16* __restrict__ qq,
    bf16* __restrict__ kk, bf16* __restrict__ vv) {
  const int nh = blockIdx.x, b = blockIdx.y, lc = blockIdx.z;
  const int l0 = lc * 128;
  __shared__ __align__(8) bf16 ut[130 * 48];
  const int t = threadIdx.x;
  for (int i = t; i < 130 * 12; i += 256) {
    const int lr = i / 12, qd = i % 12;
    const int l = l0 - 2 + lr;
    uint2 val;
    val.x = 0u; val.y = 0u;
    if (l >= 0)
      val = *(const uint2*)&u[(size_t)(b * SEQLEN + l) * INNER + nh * 48 + qd * 4];
    *(uint2*)&ut[lr * 48 + qd * 4] = val;
  }
  __syncthreads();
  const size_t bn = (size_t)(b * NUM_HEADS + nh);
#pragma unroll
  for (int s = 0; s < 2; ++s) {
    bf16* dst = (s == 0) ? qq : kk;
    const int cb = s * 16;
    for (int i = t; i < 128 * 16; i += 256) {
      const int c = i & 15, lr = i >> 4;
      const int e = nh * 48 + cb + c;
      const float val = w_sf[e * 3 + 0] * (float)ut[lr * 48 + cb + c] +
                        w_sf[e * 3 + 1] * (float)ut[(lr + 1) * 48 + cb + c] +
                        w_sf[e * 3 + 2] * (float)ut[(lr + 2) * 48 + cb + c] +
                        b_sf[e];
      dst[(bn * SEQLEN + l0 + lr) * 16 + c] = (bf16)val;
    }
  }
  for (int i = t; i < 128 * 16; i += 256) {
    const int lr = i & 127, c = i >> 7;
    const int e = nh * 48 + 32 + c;
    const float val = w_sf[e * 3 + 0] * (float)ut[lr * 48 + 32 + c] +
                      w_sf[e * 3 + 1] * (float)ut[(lr + 1) * 48 + 32 + c] +
                      w_sf[e * 3 + 2] * (float)ut[(lr + 2) * 48 + 32 + c] +
                      b_sf[e];
    vv[(bn * 16 + c) * SEQLEN + l0 + lr] = (bf16)val;
  }
}

// ---------------------------------------------------------------------------
// Causal h-weighted attention v15 (r10 double-buffered S-tile, measured
// 47.5us) + piggy-backed w_out*norm_w convert: blocks with blockIdx.x == 48
// (64 of them) convert w_out instead — u is dead here, gemm_rms consumes
// wout16 afterwards, so no race; saves one launch.
// ---------------------------------------------------------------------------
__global__ __launch_bounds__(256) void attn_kernel(
    const bf16* __restrict__ qq, const bf16* __restrict__ kk,
    const bf16* __restrict__ vv, const float* __restrict__ hg,
    bf16* __restrict__ y, const float* __restrict__ wout,
    const float* __restrict__ nw, bf16* __restrict__ wout16) {
  const int t = threadIdx.x;
  if (blockIdx.x == NUM_HEADS) {  // convert blocks
    const int cid = blockIdx.y * 32 + blockIdx.z;  // 0..63
    for (int j = cid * 256 + t; j < N4WOUT; j += 64 * 256) {
      const int d0 = (j * 4) % D_MODEL;
      const float4 v = ((const float4*)wout)[j];
      const float4 nv = *(const float4*)&nw[d0];
      bf16x4 o;
      o[0] = (bf16)(v.x * nv.x); o[1] = (bf16)(v.y * nv.y);
      o[2] = (bf16)(v.z * nv.z); o[3] = (bf16)(v.w * nv.w);
      ((bf16x4*)wout16)[j] = o;
    }
    return;
  }
  const int nh = blockIdx.x, b = blockIdx.y;
  const int qa = blockIdx.z, qb = 63 - qa;  // paired tiles
  const int l0a = qa * 32, l0b = qb * 32;
  __shared__ __align__(16) float hs[32 + SEQLEN];  // hs[32+d]=h[d], pad=0
  __shared__ __align__(16) bf16 st[8 * 32 * SST];  // 2 S-bufs per wave
  const int n4 = (l0b + 64) >> 2;
  for (int i = t; i < n4; i += 256) {
    float4 val = {0.f, 0.f, 0.f, 0.f};
    if (i >= 8) val = ((const float4*)(hg + nh * SEQLEN))[i - 8];
    ((float4*)hs)[i] = val;
  }
  __syncthreads();

  const int w = t >> 6, lane = t & 63;
  const int l31 = lane & 31, hi = lane >> 5;
  const int row16 = lane & 15, quad = lane >> 4;
  const size_t bn = (size_t)(b * NUM_HEADS + nh);
  const bf16* qp = qq + bn * SEQLEN * 16;
  const bf16* kb = kk + bn * SEQLEN * 16;
  const bf16* vb = vv + bn * 16 * SEQLEN;

  bf16x8 zf;
#pragma unroll
  for (int j = 0; j < 8; ++j) zf[j] = (bf16)0.f;
  const f32x4 zacc4 = {0.f, 0.f, 0.f, 0.f};
  f32x16 zacc16;
#pragma unroll
  for (int j = 0; j < 16; ++j) zacc16[j] = 0.f;

  const bf16x8 qfa = *(const bf16x8*)&qp[(l0a + l31) * 16 + hi * 8];
  const bf16x8 qfb = *(const bf16x8*)&qp[(l0b + l31) * 16 + hi * 8];

  bf16* sw0 = &st[(size_t)w * 2 * 32 * SST];
  bf16* sw1 = sw0 + 32 * SST;

  auto ldK = [&](int mc) { return *(const bf16x8*)&kb[(mc + l31) * 16 + hi * 8]; };
  auto ldV = [&](int mc) { return *(const bf16x8*)&vb[row16 * SEQLEN + mc + quad * 8]; };
  auto wstore = [&](const f32x16& s, const int delta, bf16* buf) {
    const int d0 = 32 + delta + l31 - 4 * hi;
#pragma unroll
    for (int g = 0; g < 4; ++g) {
      const float* hp = &hs[d0 - 8 * g - 3];
      bf16x4 pk;
      pk[0] = (bf16)(s[4 * g + 0] * hp[3]);
      pk[1] = (bf16)(s[4 * g + 1] * hp[2]);
      pk[2] = (bf16)(s[4 * g + 2] * hp[1]);
      pk[3] = (bf16)(s[4 * g + 3] * hp[0]);
      *(bf16x4*)&buf[l31 * SST + 8 * g + 4 * hi] = pk;
    }
  };
  auto pv = [&](const bf16* buf, const bf16x8 vf, f32x4& o0, f32x4& o1) {
    const bf16x8 sf0 = *(const bf16x8*)&buf[row16 * SST + quad * 8];
    const bf16x8 sf1 = *(const bf16x8*)&buf[(row16 + 16) * SST + quad * 8];
    o0 = __builtin_amdgcn_mfma_f32_16x16x32_bf16(sf0, vf, o0, 0, 0, 0);
    o1 = __builtin_amdgcn_mfma_f32_16x16x32_bf16(sf1, vf, o1, 0, 0, 0);
  };

  auto run_pass = [&](const bf16x8& qf, const int l0, const int mc0,
                      f32x4& o0, f32x4& o1) {
    int mc = mc0;
    if (mc > l0) return;
    bf16x8 k0 = ldK(mc);
    bf16x8 vf0 = ldV(mc);
    f32x16 s0 = __builtin_amdgcn_mfma_f32_32x32x16_bf16(k0, qf, zacc16, 0, 0, 0);
    bf16x8 kf1 = zf, vf1 = zf;
    if (mc + 128 <= l0) { kf1 = ldK(mc + 128); vf1 = ldV(mc + 128); }
    wstore(s0, l0 - mc, sw0);
    int p = 0;
    for (; mc + 128 <= l0; mc += 128) {
      bf16x8 kf2 = zf, vf2 = zf;
      if (mc + 256 <= l0) { kf2 = ldK(mc + 256); vf2 = ldV(mc + 256); }
      f32x16 s2 =
          __builtin_amdgcn_mfma_f32_32x32x16_bf16(kf1, qf, zacc16, 0, 0, 0);
      asm volatile("s_waitcnt lgkmcnt(0)" ::: "memory");
      pv(p ? sw1 : sw0, vf0, o0, o1);
      wstore(s2, l0 - (mc + 128), p ? sw0 : sw1);
      p ^= 1;
      kf1 = kf2; vf0 = vf1; vf1 = vf2;
    }
    asm volatile("s_waitcnt lgkmcnt(0)" ::: "memory");
    pv(p ? sw1 : sw0, vf0, o0, o1);
    asm volatile("" ::: "memory");
  };

  f32x4 o0a = zacc4, o1a = zacc4, o0b = zacc4, o1b = zacc4;
  run_pass(qfa, l0a, w * 32, o0a, o1a);
  const int j0 = ((w - qa - 1) % 4 + 4) % 4;
  run_pass(qfb, l0b, j0 * 32, o0b, o1b);

  // epilogue: two phases reusing st as 4 x (32x16 f32) reduction buffers
  float* ob = (float*)&st[(size_t)w * 2 * 32 * SST];
#pragma unroll
  for (int phase = 0; phase < 2; ++phase) {
    const f32x4& p0 = phase ? o0b : o0a;
    const f32x4& p1 = phase ? o1b : o1a;
    const int lt = phase ? l0b : l0a;
    __syncthreads();
#pragma unroll
    for (int r = 0; r < 4; ++r) {
      ob[(quad * 4 + r) * 16 + row16] = p0[r];
      ob[(quad * 4 + r + 16) * 16 + row16] = p1[r];
    }
    __syncthreads();
    for (int i = t; i < 32 * 16; i += 256) {
      const int l = i >> 4, j = i & 15;
      float sum = 0.f;
#pragma unroll
      for (int ww = 0; ww < 4; ++ww)
        sum += ((const float*)&st[(size_t)ww * 2 * 32 * SST])[l * 16 + j];
      y[((size_t)(b * SEQLEN + lt + l) * NUM_HEADS + nh) * 16 + j] = (bf16)sum;
    }
  }
}

// ---------------------------------------------------------------------------
extern "C" void kernel_launch(void* const* d_in, const int* in_sizes, int n_in,
                              void* d_out, int out_size, void* d_ws,
                              size_t ws_size, hipStream_t stream) {
  const float* inputs = (const float*)d_in[0];
  const float* w_in = (const float*)d_in[1];
  const float* b_in = (const float*)d_in[2];
  const float* w_sf = (const float*)d_in[3];
  const float* b_sf = (const float*)d_in[4];
  const float* hb = (const float*)d_in[5];
  const float* norm_w = (const float*)d_in[6];
  const float* w_out = (const float*)d_in[7];
  const float* b_out = (const float*)d_in[8];

  // ws plan (37.8 MB), region lifetimes:
  //   u   18.9 MB : GEMM1 out -> dead after conv_qkv; reused for
  //                 wout16 (+0, 1.2MB, written during attn), y16 (+9MB)
  //   v    6.3 MB : V
  //   A    6.3 MB : in16 (GEMM1 A) -> k16 (attn) -> dead
  //   B    6.3 MB : win16 (GEMM1 W, 3.5MB) -> q16 (attn)
  char* ws = (char*)d_ws;
  const size_t U_B = (size_t)M_ROWS * INNER * 2;
  const size_t V_B = (size_t)BATCH * NUM_HEADS * HEAD_CH * SEQLEN * 2;
  const size_t SLOT_B = (size_t)M_ROWS * D_MODEL * 2;
  bf16* u = (bf16*)(ws);
  bf16* wout16 = (bf16*)(ws);                    // u region, after conv
  bf16* y16 = (bf16*)(ws + (9 << 20));           // u region +9MB
  bf16* v = (bf16*)(ws + U_B);
  bf16* in16 = (bf16*)(ws + U_B + V_B);          // A
  bf16* k16 = in16;                              // A after GEMM1
  bf16* win16 = (bf16*)(ws + U_B + V_B + SLOT_B);// B
  bf16* q16 = win16;                             // B after GEMM1
  float* out = (float*)d_out;

  const int n4_in = M_ROWS * D_MODEL / 4;
  const int n4_win = INNER * D_MODEL / 4;
  hipLaunchKernelGGL(cvt2_f32_bf16, dim3((n4_in + n4_win + 255) / 256),
                     dim3(256), 0, stream, inputs, in16, n4_in, w_in, win16,
                     n4_win);

  // gemm1: 128x128 m97 geometry + XCD swizzle (576 blocks, %8==0)
  hipLaunchKernelGGL((gemm_bt<128, 128, 64, INNER, bf16>), dim3(32, 18),
                     dim3(256), 0, stream, in16, win16, b_in, u, 768);
  hipLaunchKernelGGL(conv_qkv, dim3(48, 2, 16), dim3(256), 0, stream, u, w_sf,
                     b_sf, q16, k16, v);
  // attn + piggy-backed w_out*nw convert (blockIdx.x == 48)
  hipLaunchKernelGGL(attn_kernel, dim3(49, 2, 32), dim3(256), 0, stream, q16,
                     k16, v, hb, y16, w_out, norm_w, wout16);
  // gemm2 + fused RMSNorm + skip, BK=128 (768 blocks, %8==0)
  hipLaunchKernelGGL(gemm_rms, dim3(64, 12), dim3(256), 0, stream, y16, wout16,
                     b_out, inputs, out);
}

// Round 12
// 184.392 us; speedup vs baseline: 1.0285x; 1.0033x over previous
//
#include <hip/hip_runtime.h>
#include <hip/hip_bf16.h>
#include <stdint.h>

typedef __bf16 bf16;
typedef __bf16 bf16x4 __attribute__((ext_vector_type(4)));
typedef __bf16 bf16x8 __attribute__((ext_vector_type(8)));
typedef float f32x4 __attribute__((ext_vector_type(4)));
typedef float f32x16 __attribute__((ext_vector_type(16)));

#define D_MODEL 768
#define NUM_HEADS 48
#define HEAD_CH 16
#define INNER 2304
#define BATCH 2
#define SEQLEN 2048
#define M_ROWS (BATCH * SEQLEN)
#define EPSF 1e-6f
// S-tile stride (bf16). MUST be 0 mod 8 (16B row alignment for ds_read_b128).
#define SST 40
#define N4WOUT (D_MODEL * D_MODEL / 4)

// async global->LDS, 16B per lane. LDS dest must be wave-uniform base + lane*16.
__device__ inline void gload_lds16(const void* g, void* l) {
  __builtin_amdgcn_global_load_lds((__attribute__((address_space(1))) void*)(g),
                                   (__attribute__((address_space(3))) void*)(l),
                                   16, 0, 0);
}

// XCD-aware bijective block remap (requires nwg % 8 == 0).
__device__ inline void xcd_swz(int& bx, int& by) {
  const int nx = gridDim.x;
  const int f = bx + nx * by;
  const int q = (nx * gridDim.y) >> 3;
  const int s = (f & 7) * q + (f >> 3);
  bx = s % nx;
  by = s / nx;
}

// ---------------------------------------------------------------------------
// fused dual f32 -> bf16 convert (two independent tensors, one launch)
// ---------------------------------------------------------------------------
__global__ __launch_bounds__(256) void cvt2_f32_bf16(
    const float* __restrict__ a, bf16* __restrict__ da, int na4,
    const float* __restrict__ b, bf16* __restrict__ db, int nb4) {
  int j = blockIdx.x * 256 + threadIdx.x;
  const float* s;
  bf16* d;
  if (j < na4) {
    s = a; d = da;
  } else {
    j -= na4;
    if (j >= nb4) return;
    s = b; d = db;
  }
  const float4 v = ((const float4*)s)[j];
  bf16x4 o;
  o[0] = (bf16)v.x; o[1] = (bf16)v.y; o[2] = (bf16)v.z; o[3] = (bf16)v.w;
  ((bf16x4*)d)[j] = o;
}

// ---------------------------------------------------------------------------
// GEMM1: C[m,n] = sum_k A[m,k]*W[n,k] + bias[n]; m97 pattern, 128x128, BK=64.
// ---------------------------------------------------------------------------
template <int TM, int TN, int BK, int NCOLS, typename CT>
__global__ __launch_bounds__(256) void gemm_bt(
    const bf16* __restrict__ A, const bf16* __restrict__ W,
    const float* __restrict__ bias, CT* __restrict__ C, int K) {
  constexpr int MI = TM / 32;
  constexpr int NI = TN / 32;
  constexpr int KK = BK / 32;
  __shared__ __align__(16) bf16 As[TM * BK];
  __shared__ __align__(16) bf16 Bs[TN * BK];
  const int t = threadIdx.x;
  const int lane = t & 63, w = t >> 6;
  const int wm = (w >> 1) * (TM / 2), wn = (w & 1) * (TN / 2);
  const int row16 = lane & 15, quad = lane >> 4;
  int bx = blockIdx.x, by = blockIdx.y;
  xcd_swz(bx, by);
  const int m0 = bx * TM, n0 = by * TN;

  f32x4 zero4 = {0.f, 0.f, 0.f, 0.f};
  f32x4 acc[MI][NI];
#pragma unroll
  for (int mi = 0; mi < MI; ++mi)
#pragma unroll
    for (int ni = 0; ni < NI; ++ni) acc[mi][ni] = zero4;

  const int arow = t >> 2;        // 0..63
  const int acol = (t & 3) * 8;   // 0..24
  const bf16* Ab = A + (size_t)m0 * K;
  const bf16* Wb = W + (size_t)n0 * K;

  for (int kt = 0; kt < K; kt += BK) {
#pragma unroll
    for (int kk0 = 0; kk0 < KK; ++kk0) {
#pragma unroll
      for (int rh = 0; rh < TM / 64; ++rh)
        gload_lds16(Ab + (size_t)(rh * 64 + arow) * K + kt + kk0 * 32 + acol,
                    As + kk0 * (TM * 32) + rh * 2048 + t * 8);
#pragma unroll
      for (int rh = 0; rh < TN / 64; ++rh)
        gload_lds16(Wb + (size_t)(rh * 64 + arow) * K + kt + kk0 * 32 + acol,
                    Bs + kk0 * (TN * 32) + rh * 2048 + t * 8);
    }
    __syncthreads();

    bf16x8 af[MI][KK], wf[NI][KK];
#pragma unroll
    for (int kk0 = 0; kk0 < KK; ++kk0) {
#pragma unroll
      for (int mi = 0; mi < MI; ++mi)
        af[mi][kk0] = *(const bf16x8*)&As[kk0 * (TM * 32) +
                                          (wm + mi * 16 + row16) * 32 +
                                          quad * 8];
#pragma unroll
      for (int ni = 0; ni < NI; ++ni)
        wf[ni][kk0] = *(const bf16x8*)&Bs[kk0 * (TN * 32) +
                                          (wn + ni * 16 + row16) * 32 +
                                          quad * 8];
    }
#pragma unroll
    for (int kk0 = 0; kk0 < KK; ++kk0)
#pragma unroll
      for (int mi = 0; mi < MI; ++mi)
#pragma unroll
        for (int ni = 0; ni < NI; ++ni)
          acc[mi][ni] = __builtin_amdgcn_mfma_f32_16x16x32_bf16(
              af[mi][kk0], wf[ni][kk0], acc[mi][ni], 0, 0, 0);
    __syncthreads();
  }

#pragma unroll
  for (int mi = 0; mi < MI; ++mi) {
#pragma unroll
    for (int ni = 0; ni < NI; ++ni) {
      const int col = n0 + wn + ni * 16 + row16;
      const float bv = bias[col];
#pragma unroll
      for (int r = 0; r < 4; ++r) {
        const int row = m0 + wm + mi * 16 + quad * 4 + r;
        C[(size_t)row * NCOLS + col] = (CT)(acc[mi][ni][r] + bv);
      }
    }
  }
}

// ---------------------------------------------------------------------------
// GEMM2 + fused RMSNorm, 64x64 tile, BK=128 (6 K-iters vs 12).
// out = r[m]*sum y*W' + b + skip. W' = w_out*nw.
// ---------------------------------------------------------------------------
__global__ __launch_bounds__(256) void gemm_rms(
    const bf16* __restrict__ A, const bf16* __restrict__ W,
    const float* __restrict__ bias, const float* __restrict__ skip,
    float* __restrict__ C) {
  constexpr int TM = 64, TN = 64, BK = 128, K = D_MODEL;
  constexpr int MI = 2, NI = 2, KK = 4;
  __shared__ __align__(16) bf16 As[TM * BK];  // 16 KB, [kk0][64][32]
  __shared__ __align__(16) bf16 Bs[TN * BK];  // 16 KB
  __shared__ float rs[TM];
  const int t = threadIdx.x;
  const int lane = t & 63, w = t >> 6;
  const int wm = (w >> 1) * 32, wn = (w & 1) * 32;
  const int row16 = lane & 15, quad = lane >> 4;
  int bx = blockIdx.x, by = blockIdx.y;
  xcd_swz(bx, by);
  const int m0 = bx * TM, n0 = by * TN;

  f32x4 zero4 = {0.f, 0.f, 0.f, 0.f};
  f32x4 acc[MI][NI];
#pragma unroll
  for (int mi = 0; mi < MI; ++mi)
#pragma unroll
    for (int ni = 0; ni < NI; ++ni) acc[mi][ni] = zero4;

  const int arow = t >> 2;
  const int acol = (t & 3) * 8;
  const bf16* Ab = A + (size_t)m0 * K;
  const bf16* Wb = W + (size_t)n0 * K;
  float ssq = 0.f;

  for (int kt = 0; kt < K; kt += BK) {
#pragma unroll
    for (int kk0 = 0; kk0 < KK; ++kk0) {
      gload_lds16(Ab + (size_t)arow * K + kt + kk0 * 32 + acol,
                  As + kk0 * (TM * 32) + t * 8);
      gload_lds16(Wb + (size_t)arow * K + kt + kk0 * 32 + acol,
                  Bs + kk0 * (TN * 32) + t * 8);
    }
    __syncthreads();

    bf16x8 af[MI][KK], wf[NI][KK];
#pragma unroll
    for (int kk0 = 0; kk0 < KK; ++kk0) {
#pragma unroll
      for (int mi = 0; mi < MI; ++mi)
        af[mi][kk0] = *(const bf16x8*)&As[kk0 * (TM * 32) +
                                          (wm + mi * 16 + row16) * 32 +
                                          quad * 8];
#pragma unroll
      for (int ni = 0; ni < NI; ++ni)
        wf[ni][kk0] = *(const bf16x8*)&Bs[kk0 * (TN * 32) +
                                          (wn + ni * 16 + row16) * 32 +
                                          quad * 8];
    }
    // ssq partial: exactly the elements this thread DMA'd
#pragma unroll
    for (int kk0 = 0; kk0 < KK; ++kk0) {
      const bf16x8 q = *(const bf16x8*)&As[kk0 * (TM * 32) + t * 8];
#pragma unroll
      for (int jj = 0; jj < 8; ++jj) {
        const float f = (float)q[jj];
        ssq += f * f;
      }
    }
#pragma unroll
    for (int kk0 = 0; kk0 < KK; ++kk0)
#pragma unroll
      for (int mi = 0; mi < MI; ++mi)
#pragma unroll
        for (int ni = 0; ni < NI; ++ni)
          acc[mi][ni] = __builtin_amdgcn_mfma_f32_16x16x32_bf16(
              af[mi][kk0], wf[ni][kk0], acc[mi][ni], 0, 0, 0);
    __syncthreads();
  }

  // reduce ssq (4 threads per row) -> rs[row]
  float* ssr = (float*)As;  // As dead after loop
  ssr[t] = ssq;
  __syncthreads();
  if (t < TM) {
    const float s4 = ssr[4 * t] + ssr[4 * t + 1] + ssr[4 * t + 2] + ssr[4 * t + 3];
    rs[t] = rsqrtf(s4 * (1.f / (float)D_MODEL) + EPSF);
  }
  __syncthreads();

#pragma unroll
  for (int mi = 0; mi < MI; ++mi) {
#pragma unroll
    for (int ni = 0; ni < NI; ++ni) {
      const int col = n0 + wn + ni * 16 + row16;
      const float bv = bias[col];
#pragma unroll
      for (int r = 0; r < 4; ++r) {
        const int rowl = wm + mi * 16 + quad * 4 + r;
        const int row = m0 + rowl;
        C[(size_t)row * D_MODEL + col] =
            acc[mi][ni][r] * rs[rowl] + bv + skip[(size_t)row * D_MODEL + col];
      }
    }
  }
}

// ---------------------------------------------------------------------------
// Q+K+V causal width-3 conv from u (r8-exact scalar version):
//   ch 0..15  -> Q (B,N,L,16);  16..31 -> K (B,N,L,16);  32..47 -> V (B,N,16,L)
// ---------------------------------------------------------------------------
__global__ __launch_bounds__(256) void conv_qkv(
    const bf16* __restrict__ u, const float* __restrict__ w_sf,
    const float* __restrict__ b_sf, bf16* __restrict__ qq,
    bf16* __restrict__ kk, bf16* __restrict__ vv) {
  const int nh = blockIdx.x, b = blockIdx.y, lc = blockIdx.z;
  const int l0 = lc * 128;
  __shared__ __align__(8) bf16 ut[130 * 48];
  const int t = threadIdx.x;
  for (int i = t; i < 130 * 12; i += 256) {
    const int lr = i / 12, qd = i % 12;
    const int l = l0 - 2 + lr;
    uint2 val;
    val.x = 0u; val.y = 0u;
    if (l >= 0)
      val = *(const uint2*)&u[(size_t)(b * SEQLEN + l) * INNER + nh * 48 + qd * 4];
    *(uint2*)&ut[lr * 48 + qd * 4] = val;
  }
  __syncthreads();
  const size_t bn = (size_t)(b * NUM_HEADS + nh);
#pragma unroll
  for (int s = 0; s < 2; ++s) {
    bf16* dst = (s == 0) ? qq : kk;
    const int cb = s * 16;
    for (int i = t; i < 128 * 16; i += 256) {
      const int c = i & 15, lr = i >> 4;
      const int e = nh * 48 + cb + c;
      const float val = w_sf[e * 3 + 0] * (float)ut[lr * 48 + cb + c] +
                        w_sf[e * 3 + 1] * (float)ut[(lr + 1) * 48 + cb + c] +
                        w_sf[e * 3 + 2] * (float)ut[(lr + 2) * 48 + cb + c] +
                        b_sf[e];
      dst[(bn * SEQLEN + l0 + lr) * 16 + c] = (bf16)val;
    }
  }
  for (int i = t; i < 128 * 16; i += 256) {
    const int lr = i & 127, c = i >> 7;
    const int e = nh * 48 + 32 + c;
    const float val = w_sf[e * 3 + 0] * (float)ut[lr * 48 + 32 + c] +
                      w_sf[e * 3 + 1] * (float)ut[(lr + 1) * 48 + 32 + c] +
                      w_sf[e * 3 + 2] * (float)ut[(lr + 2) * 48 + 32 + c] +
                      b_sf[e];
    vv[(bn * 16 + c) * SEQLEN + l0 + lr] = (bf16)val;
  }
}

// ---------------------------------------------------------------------------
// Causal h-weighted attention v15 (r10 double-buffered S-tile, 47.5us) +
// w_out*norm_w convert fused on the Z-DIMENSION (blockIdx.z == 32, 96
// blocks): appending on z keeps attn blocks' linear IDs (x + 48*(y+2z))
// and thus their XCD mapping EXACTLY as r10 — r11 widened x to 49 (coprime
// with 8 XCDs), destroying per-XCD head locality (FETCH 10.8->103MB).
// ---------------------------------------------------------------------------
__global__ __launch_bounds__(256) void attn_kernel(
    const bf16* __restrict__ qq, const bf16* __restrict__ kk,
    const bf16* __restrict__ vv, const float* __restrict__ hg,
    bf16* __restrict__ y, const float* __restrict__ wout,
    const float* __restrict__ nw, bf16* __restrict__ wout16) {
  const int t = threadIdx.x;
  if (blockIdx.z == 32) {  // convert blocks (96)
    const int cid = blockIdx.x + NUM_HEADS * blockIdx.y;  // 0..95
    for (int j = cid * 256 + t; j < N4WOUT; j += 96 * 256) {
      const int d0 = (j * 4) % D_MODEL;
      const float4 v = ((const float4*)wout)[j];
      const float4 nv = *(const float4*)&nw[d0];
      bf16x4 o;
      o[0] = (bf16)(v.x * nv.x); o[1] = (bf16)(v.y * nv.y);
      o[2] = (bf16)(v.z * nv.z); o[3] = (bf16)(v.w * nv.w);
      ((bf16x4*)wout16)[j] = o;
    }
    return;
  }
  const int nh = blockIdx.x, b = blockIdx.y;
  const int qa = blockIdx.z, qb = 63 - qa;  // paired tiles
  const int l0a = qa * 32, l0b = qb * 32;
  __shared__ __align__(16) float hs[32 + SEQLEN];  // hs[32+d]=h[d], pad=0
  __shared__ __align__(16) bf16 st[8 * 32 * SST];  // 2 S-bufs per wave
  const int n4 = (l0b + 64) >> 2;
  for (int i = t; i < n4; i += 256) {
    float4 val = {0.f, 0.f, 0.f, 0.f};
    if (i >= 8) val = ((const float4*)(hg + nh * SEQLEN))[i - 8];
    ((float4*)hs)[i] = val;
  }
  __syncthreads();

  const int w = t >> 6, lane = t & 63;
  const int l31 = lane & 31, hi = lane >> 5;
  const int row16 = lane & 15, quad = lane >> 4;
  const size_t bn = (size_t)(b * NUM_HEADS + nh);
  const bf16* qp = qq + bn * SEQLEN * 16;
  const bf16* kb = kk + bn * SEQLEN * 16;
  const bf16* vb = vv + bn * 16 * SEQLEN;

  bf16x8 zf;
#pragma unroll
  for (int j = 0; j < 8; ++j) zf[j] = (bf16)0.f;
  const f32x4 zacc4 = {0.f, 0.f, 0.f, 0.f};
  f32x16 zacc16;
#pragma unroll
  for (int j = 0; j < 16; ++j) zacc16[j] = 0.f;

  const bf16x8 qfa = *(const bf16x8*)&qp[(l0a + l31) * 16 + hi * 8];
  const bf16x8 qfb = *(const bf16x8*)&qp[(l0b + l31) * 16 + hi * 8];

  bf16* sw0 = &st[(size_t)w * 2 * 32 * SST];
  bf16* sw1 = sw0 + 32 * SST;

  auto ldK = [&](int mc) { return *(const bf16x8*)&kb[(mc + l31) * 16 + hi * 8]; };
  auto ldV = [&](int mc) { return *(const bf16x8*)&vb[row16 * SEQLEN + mc + quad * 8]; };
  auto wstore = [&](const f32x16& s, const int delta, bf16* buf) {
    const int d0 = 32 + delta + l31 - 4 * hi;
#pragma unroll
    for (int g = 0; g < 4; ++g) {
      const float* hp = &hs[d0 - 8 * g - 3];
      bf16x4 pk;
      pk[0] = (bf16)(s[4 * g + 0] * hp[3]);
      pk[1] = (bf16)(s[4 * g + 1] * hp[2]);
      pk[2] = (bf16)(s[4 * g + 2] * hp[1]);
      pk[3] = (bf16)(s[4 * g + 3] * hp[0]);
      *(bf16x4*)&buf[l31 * SST + 8 * g + 4 * hi] = pk;
    }
  };
  auto pv = [&](const bf16* buf, const bf16x8 vf, f32x4& o0, f32x4& o1) {
    const bf16x8 sf0 = *(const bf16x8*)&buf[row16 * SST + quad * 8];
    const bf16x8 sf1 = *(const bf16x8*)&buf[(row16 + 16) * SST + quad * 8];
    o0 = __builtin_amdgcn_mfma_f32_16x16x32_bf16(sf0, vf, o0, 0, 0, 0);
    o1 = __builtin_amdgcn_mfma_f32_16x16x32_bf16(sf1, vf, o1, 0, 0, 0);
  };

  auto run_pass = [&](const bf16x8& qf, const int l0, const int mc0,
                      f32x4& o0, f32x4& o1) {
    int mc = mc0;
    if (mc > l0) return;
    bf16x8 k0 = ldK(mc);
    bf16x8 vf0 = ldV(mc);
    f32x16 s0 = __builtin_amdgcn_mfma_f32_32x32x16_bf16(k0, qf, zacc16, 0, 0, 0);
    bf16x8 kf1 = zf, vf1 = zf;
    if (mc + 128 <= l0) { kf1 = ldK(mc + 128); vf1 = ldV(mc + 128); }
    wstore(s0, l0 - mc, sw0);
    int p = 0;
    for (; mc + 128 <= l0; mc += 128) {
      bf16x8 kf2 = zf, vf2 = zf;
      if (mc + 256 <= l0) { kf2 = ldK(mc + 256); vf2 = ldV(mc + 256); }
      f32x16 s2 =
          __builtin_amdgcn_mfma_f32_32x32x16_bf16(kf1, qf, zacc16, 0, 0, 0);
      asm volatile("s_waitcnt lgkmcnt(0)" ::: "memory");
      pv(p ? sw1 : sw0, vf0, o0, o1);
      wstore(s2, l0 - (mc + 128), p ? sw0 : sw1);
      p ^= 1;
      kf1 = kf2; vf0 = vf1; vf1 = vf2;
    }
    asm volatile("s_waitcnt lgkmcnt(0)" ::: "memory");
    pv(p ? sw1 : sw0, vf0, o0, o1);
    asm volatile("" ::: "memory");
  };

  f32x4 o0a = zacc4, o1a = zacc4, o0b = zacc4, o1b = zacc4;
  run_pass(qfa, l0a, w * 32, o0a, o1a);
  const int j0 = ((w - qa - 1) % 4 + 4) % 4;
  run_pass(qfb, l0b, j0 * 32, o0b, o1b);

  // epilogue: two phases reusing st as 4 x (32x16 f32) reduction buffers
  float* ob = (float*)&st[(size_t)w * 2 * 32 * SST];
#pragma unroll
  for (int phase = 0; phase < 2; ++phase) {
    const f32x4& p0 = phase ? o0b : o0a;
    const f32x4& p1 = phase ? o1b : o1a;
    const int lt = phase ? l0b : l0a;
    __syncthreads();
#pragma unroll
    for (int r = 0; r < 4; ++r) {
      ob[(quad * 4 + r) * 16 + row16] = p0[r];
      ob[(quad * 4 + r + 16) * 16 + row16] = p1[r];
    }
    __syncthreads();
    for (int i = t; i < 32 * 16; i += 256) {
      const int l = i >> 4, j = i & 15;
      float sum = 0.f;
#pragma unroll
      for (int ww = 0; ww < 4; ++ww)
        sum += ((const float*)&st[(size_t)ww * 2 * 32 * SST])[l * 16 + j];
      y[((size_t)(b * SEQLEN + lt + l) * NUM_HEADS + nh) * 16 + j] = (bf16)sum;
    }
  }
}

// ---------------------------------------------------------------------------
extern "C" void kernel_launch(void* const* d_in, const int* in_sizes, int n_in,
                              void* d_out, int out_size, void* d_ws,
                              size_t ws_size, hipStream_t stream) {
  const float* inputs = (const float*)d_in[0];
  const float* w_in = (const float*)d_in[1];
  const float* b_in = (const float*)d_in[2];
  const float* w_sf = (const float*)d_in[3];
  const float* b_sf = (const float*)d_in[4];
  const float* hb = (const float*)d_in[5];
  const float* norm_w = (const float*)d_in[6];
  const float* w_out = (const float*)d_in[7];
  const float* b_out = (const float*)d_in[8];

  // ws plan (37.8 MB), region lifetimes:
  //   u   18.9 MB : GEMM1 out -> dead after conv_qkv; reused for
  //                 wout16 (+0, 1.2MB, written during attn), y16 (+9MB)
  //   v    6.3 MB : V
  //   A    6.3 MB : in16 (GEMM1 A) -> k16 (attn) -> dead
  //   B    6.3 MB : win16 (GEMM1 W, 3.5MB) -> q16 (attn)
  char* ws = (char*)d_ws;
  const size_t U_B = (size_t)M_ROWS * INNER * 2;
  const size_t V_B = (size_t)BATCH * NUM_HEADS * HEAD_CH * SEQLEN * 2;
  const size_t SLOT_B = (size_t)M_ROWS * D_MODEL * 2;
  bf16* u = (bf16*)(ws);
  bf16* wout16 = (bf16*)(ws);                    // u region, after conv
  bf16* y16 = (bf16*)(ws + (9 << 20));           // u region +9MB
  bf16* v = (bf16*)(ws + U_B);
  bf16* in16 = (bf16*)(ws + U_B + V_B);          // A
  bf16* k16 = in16;                              // A after GEMM1
  bf16* win16 = (bf16*)(ws + U_B + V_B + SLOT_B);// B
  bf16* q16 = win16;                             // B after GEMM1
  float* out = (float*)d_out;

  const int n4_in = M_ROWS * D_MODEL / 4;
  const int n4_win = INNER * D_MODEL / 4;
  hipLaunchKernelGGL(cvt2_f32_bf16, dim3((n4_in + n4_win + 255) / 256),
                     dim3(256), 0, stream, inputs, in16, n4_in, w_in, win16,
                     n4_win);

  // gemm1: 128x128 m97 geometry + XCD swizzle (576 blocks, %8==0)
  hipLaunchKernelGGL((gemm_bt<128, 128, 64, INNER, bf16>), dim3(32, 18),
                     dim3(256), 0, stream, in16, win16, b_in, u, 768);
  hipLaunchKernelGGL(conv_qkv, dim3(48, 2, 16), dim3(256), 0, stream, u, w_sf,
                     b_sf, q16, k16, v);
  // attn + w_out*nw convert fused on z (blockIdx.z == 32)
  hipLaunchKernelGGL(attn_kernel, dim3(48, 2, 33), dim3(256), 0, stream, q16,
                     k16, v, hb, y16, w_out, norm_w, wout16);
  // gemm2 + fused RMSNorm + skip, BK=128 (768 blocks, %8==0)
  hipLaunchKernelGGL(gemm_rms, dim3(64, 12), dim3(256), 0, stream, y16, wout16,
                     b_out, inputs, out);
}

// Round 13
// 179.242 us; speedup vs baseline: 1.0580x; 1.0287x over previous
//
#include <hip/hip_runtime.h>
#include <hip/hip_bf16.h>
#include <stdint.h>

typedef __bf16 bf16;
typedef __bf16 bf16x4 __attribute__((ext_vector_type(4)));
typedef __bf16 bf16x8 __attribute__((ext_vector_type(8)));
typedef float f32x4 __attribute__((ext_vector_type(4)));
typedef float f32x16 __attribute__((ext_vector_type(16)));

#define D_MODEL 768
#define NUM_HEADS 48
#define HEAD_CH 16
#define INNER 2304
#define BATCH 2
#define SEQLEN 2048
#define M_ROWS (BATCH * SEQLEN)
#define EPSF 1e-6f
// S-tile stride (bf16). MUST be 0 mod 8 (16B row alignment for ds_read_b128).
#define SST 40
#define N4WOUT (D_MODEL * D_MODEL / 4)

// async global->LDS, 16B per lane. LDS dest must be wave-uniform base + lane*16.
__device__ inline void gload_lds16(const void* g, void* l) {
  __builtin_amdgcn_global_load_lds((__attribute__((address_space(1))) void*)(g),
                                   (__attribute__((address_space(3))) void*)(l),
                                   16, 0, 0);
}

// XCD-aware bijective block remap (requires nwg % 8 == 0).
__device__ inline void xcd_swz(int& bx, int& by) {
  const int nx = gridDim.x;
  const int f = bx + nx * by;
  const int q = (nx * gridDim.y) >> 3;
  const int s = (f & 7) * q + (f >> 3);
  bx = s % nx;
  by = s / nx;
}

// ---------------------------------------------------------------------------
// fused dual f32 -> bf16 convert (two independent tensors, one launch)
// ---------------------------------------------------------------------------
__global__ __launch_bounds__(256) void cvt2_f32_bf16(
    const float* __restrict__ a, bf16* __restrict__ da, int na4,
    const float* __restrict__ b, bf16* __restrict__ db, int nb4) {
  int j = blockIdx.x * 256 + threadIdx.x;
  const float* s;
  bf16* d;
  if (j < na4) {
    s = a; d = da;
  } else {
    j -= na4;
    if (j >= nb4) return;
    s = b; d = db;
  }
  const float4 v = ((const float4*)s)[j];
  bf16x4 o;
  o[0] = (bf16)v.x; o[1] = (bf16)v.y; o[2] = (bf16)v.z; o[3] = (bf16)v.w;
  ((bf16x4*)d)[j] = o;
}

// ---------------------------------------------------------------------------
// GEMM1: C[m,n] = sum_k A[m,k]*W[n,k] + bias[n]; m97 pattern, 128x128, BK=64.
// ---------------------------------------------------------------------------
template <int TM, int TN, int BK, int NCOLS, typename CT>
__global__ __launch_bounds__(256) void gemm_bt(
    const bf16* __restrict__ A, const bf16* __restrict__ W,
    const float* __restrict__ bias, CT* __restrict__ C, int K) {
  constexpr int MI = TM / 32;
  constexpr int NI = TN / 32;
  constexpr int KK = BK / 32;
  __shared__ __align__(16) bf16 As[TM * BK];
  __shared__ __align__(16) bf16 Bs[TN * BK];
  const int t = threadIdx.x;
  const int lane = t & 63, w = t >> 6;
  const int wm = (w >> 1) * (TM / 2), wn = (w & 1) * (TN / 2);
  const int row16 = lane & 15, quad = lane >> 4;
  int bx = blockIdx.x, by = blockIdx.y;
  xcd_swz(bx, by);
  const int m0 = bx * TM, n0 = by * TN;

  f32x4 zero4 = {0.f, 0.f, 0.f, 0.f};
  f32x4 acc[MI][NI];
#pragma unroll
  for (int mi = 0; mi < MI; ++mi)
#pragma unroll
    for (int ni = 0; ni < NI; ++ni) acc[mi][ni] = zero4;

  const int arow = t >> 2;        // 0..63
  const int acol = (t & 3) * 8;   // 0..24
  const bf16* Ab = A + (size_t)m0 * K;
  const bf16* Wb = W + (size_t)n0 * K;

  for (int kt = 0; kt < K; kt += BK) {
#pragma unroll
    for (int kk0 = 0; kk0 < KK; ++kk0) {
#pragma unroll
      for (int rh = 0; rh < TM / 64; ++rh)
        gload_lds16(Ab + (size_t)(rh * 64 + arow) * K + kt + kk0 * 32 + acol,
                    As + kk0 * (TM * 32) + rh * 2048 + t * 8);
#pragma unroll
      for (int rh = 0; rh < TN / 64; ++rh)
        gload_lds16(Wb + (size_t)(rh * 64 + arow) * K + kt + kk0 * 32 + acol,
                    Bs + kk0 * (TN * 32) + rh * 2048 + t * 8);
    }
    __syncthreads();

    bf16x8 af[MI][KK], wf[NI][KK];
#pragma unroll
    for (int kk0 = 0; kk0 < KK; ++kk0) {
#pragma unroll
      for (int mi = 0; mi < MI; ++mi)
        af[mi][kk0] = *(const bf16x8*)&As[kk0 * (TM * 32) +
                                          (wm + mi * 16 + row16) * 32 +
                                          quad * 8];
#pragma unroll
      for (int ni = 0; ni < NI; ++ni)
        wf[ni][kk0] = *(const bf16x8*)&Bs[kk0 * (TN * 32) +
                                          (wn + ni * 16 + row16) * 32 +
                                          quad * 8];
    }
#pragma unroll
    for (int kk0 = 0; kk0 < KK; ++kk0)
#pragma unroll
      for (int mi = 0; mi < MI; ++mi)
#pragma unroll
        for (int ni = 0; ni < NI; ++ni)
          acc[mi][ni] = __builtin_amdgcn_mfma_f32_16x16x32_bf16(
              af[mi][kk0], wf[ni][kk0], acc[mi][ni], 0, 0, 0);
    __syncthreads();
  }

#pragma unroll
  for (int mi = 0; mi < MI; ++mi) {
#pragma unroll
    for (int ni = 0; ni < NI; ++ni) {
      const int col = n0 + wn + ni * 16 + row16;
      const float bv = bias[col];
#pragma unroll
      for (int r = 0; r < 4; ++r) {
        const int row = m0 + wm + mi * 16 + quad * 4 + r;
        C[(size_t)row * NCOLS + col] = (CT)(acc[mi][ni][r] + bv);
      }
    }
  }
}

// ---------------------------------------------------------------------------
// GEMM2 + fused RMSNorm (r8-exact: 64x64, BK=64, 16.25KB LDS — BK=128 was
// isolated as a ~+4us regression in r10/r12 vs r8, m132 precedent).
// out = r[m]*sum y*W' + b + skip. W' = w_out*nw.
// ---------------------------------------------------------------------------
__global__ __launch_bounds__(256) void gemm_rms(
    const bf16* __restrict__ A, const bf16* __restrict__ W,
    const float* __restrict__ bias, const float* __restrict__ skip,
    float* __restrict__ C) {
  constexpr int TM = 64, TN = 64, BK = 64, K = D_MODEL;
  constexpr int MI = 2, NI = 2, KK = 2;
  __shared__ __align__(16) bf16 As[TM * BK];
  __shared__ __align__(16) bf16 Bs[TN * BK];
  __shared__ float rs[TM];
  const int t = threadIdx.x;
  const int lane = t & 63, w = t >> 6;
  const int wm = (w >> 1) * 32, wn = (w & 1) * 32;
  const int row16 = lane & 15, quad = lane >> 4;
  int bx = blockIdx.x, by = blockIdx.y;
  xcd_swz(bx, by);
  const int m0 = bx * TM, n0 = by * TN;

  f32x4 zero4 = {0.f, 0.f, 0.f, 0.f};
  f32x4 acc[MI][NI];
#pragma unroll
  for (int mi = 0; mi < MI; ++mi)
#pragma unroll
    for (int ni = 0; ni < NI; ++ni) acc[mi][ni] = zero4;

  const int arow = t >> 2;
  const int acol = (t & 3) * 8;
  const bf16* Ab = A + (size_t)m0 * K;
  const bf16* Wb = W + (size_t)n0 * K;
  float ssq = 0.f;

  for (int kt = 0; kt < K; kt += BK) {
#pragma unroll
    for (int kk0 = 0; kk0 < KK; ++kk0) {
      gload_lds16(Ab + (size_t)arow * K + kt + kk0 * 32 + acol,
                  As + kk0 * (TM * 32) + t * 8);
      gload_lds16(Wb + (size_t)arow * K + kt + kk0 * 32 + acol,
                  Bs + kk0 * (TN * 32) + t * 8);
    }
    __syncthreads();

    bf16x8 af[MI][KK], wf[NI][KK];
#pragma unroll
    for (int kk0 = 0; kk0 < KK; ++kk0) {
#pragma unroll
      for (int mi = 0; mi < MI; ++mi)
        af[mi][kk0] = *(const bf16x8*)&As[kk0 * (TM * 32) +
                                          (wm + mi * 16 + row16) * 32 +
                                          quad * 8];
#pragma unroll
      for (int ni = 0; ni < NI; ++ni)
        wf[ni][kk0] = *(const bf16x8*)&Bs[kk0 * (TN * 32) +
                                          (wn + ni * 16 + row16) * 32 +
                                          quad * 8];
    }
    // ssq partial: thread t covers row t>>2, cols (t&3)*8..+8 of both kk0
#pragma unroll
    for (int kk0 = 0; kk0 < KK; ++kk0) {
      const bf16x8 q =
          *(const bf16x8*)&As[kk0 * (TM * 32) + (t >> 2) * 32 + (t & 3) * 8];
#pragma unroll
      for (int jj = 0; jj < 8; ++jj) {
        const float f = (float)q[jj];
        ssq += f * f;
      }
    }
#pragma unroll
    for (int kk0 = 0; kk0 < KK; ++kk0)
#pragma unroll
      for (int mi = 0; mi < MI; ++mi)
#pragma unroll
        for (int ni = 0; ni < NI; ++ni)
          acc[mi][ni] = __builtin_amdgcn_mfma_f32_16x16x32_bf16(
              af[mi][kk0], wf[ni][kk0], acc[mi][ni], 0, 0, 0);
    __syncthreads();
  }

  // reduce ssq (4 threads per row) -> rs[row]
  float* ssr = (float*)As;  // As dead after loop
  ssr[t] = ssq;
  __syncthreads();
  if (t < TM) {
    const float s4 = ssr[4 * t] + ssr[4 * t + 1] + ssr[4 * t + 2] + ssr[4 * t + 3];
    rs[t] = rsqrtf(s4 * (1.f / (float)D_MODEL) + EPSF);
  }
  __syncthreads();

#pragma unroll
  for (int mi = 0; mi < MI; ++mi) {
#pragma unroll
    for (int ni = 0; ni < NI; ++ni) {
      const int col = n0 + wn + ni * 16 + row16;
      const float bv = bias[col];
#pragma unroll
      for (int r = 0; r < 4; ++r) {
        const int rowl = wm + mi * 16 + quad * 4 + r;
        const int row = m0 + rowl;
        C[(size_t)row * D_MODEL + col] =
            acc[mi][ni][r] * rs[rowl] + bv + skip[(size_t)row * D_MODEL + col];
      }
    }
  }
}

// ---------------------------------------------------------------------------
// Q+K+V causal width-3 conv from u (r8-exact scalar version):
//   ch 0..15  -> Q (B,N,L,16);  16..31 -> K (B,N,L,16);  32..47 -> V (B,N,16,L)
// ---------------------------------------------------------------------------
__global__ __launch_bounds__(256) void conv_qkv(
    const bf16* __restrict__ u, const float* __restrict__ w_sf,
    const float* __restrict__ b_sf, bf16* __restrict__ qq,
    bf16* __restrict__ kk, bf16* __restrict__ vv) {
  const int nh = blockIdx.x, b = blockIdx.y, lc = blockIdx.z;
  const int l0 = lc * 128;
  __shared__ __align__(8) bf16 ut[130 * 48];
  const int t = threadIdx.x;
  for (int i = t; i < 130 * 12; i += 256) {
    const int lr = i / 12, qd = i % 12;
    const int l = l0 - 2 + lr;
    uint2 val;
    val.x = 0u; val.y = 0u;
    if (l >= 0)
      val = *(const uint2*)&u[(size_t)(b * SEQLEN + l) * INNER + nh * 48 + qd * 4];
    *(uint2*)&ut[lr * 48 + qd * 4] = val;
  }
  __syncthreads();
  const size_t bn = (size_t)(b * NUM_HEADS + nh);
#pragma unroll
  for (int s = 0; s < 2; ++s) {
    bf16* dst = (s == 0) ? qq : kk;
    const int cb = s * 16;
    for (int i = t; i < 128 * 16; i += 256) {
      const int c = i & 15, lr = i >> 4;
      const int e = nh * 48 + cb + c;
      const float val = w_sf[e * 3 + 0] * (float)ut[lr * 48 + cb + c] +
                        w_sf[e * 3 + 1] * (float)ut[(lr + 1) * 48 + cb + c] +
                        w_sf[e * 3 + 2] * (float)ut[(lr + 2) * 48 + cb + c] +
                        b_sf[e];
      dst[(bn * SEQLEN + l0 + lr) * 16 + c] = (bf16)val;
    }
  }
  for (int i = t; i < 128 * 16; i += 256) {
    const int lr = i & 127, c = i >> 7;
    const int e = nh * 48 + 32 + c;
    const float val = w_sf[e * 3 + 0] * (float)ut[lr * 48 + 32 + c] +
                      w_sf[e * 3 + 1] * (float)ut[(lr + 1) * 48 + 32 + c] +
                      w_sf[e * 3 + 2] * (float)ut[(lr + 2) * 48 + 32 + c] +
                      b_sf[e];
    vv[(bn * 16 + c) * SEQLEN + l0 + lr] = (bf16)val;
  }
}

// ---------------------------------------------------------------------------
// Causal h-weighted attention v15 (r10 double-buffered S-tile) + w_out*nw
// convert fused on the Z-DIMENSION (blockIdx.z == 32): z-append keeps attn
// blocks' linear IDs and XCD mapping (r11's x-append destroyed head->XCD
// locality: FETCH 10.8->103MB; r12 confirmed z-append restores ~12MB).
// ---------------------------------------------------------------------------
__global__ __launch_bounds__(256) void attn_kernel(
    const bf16* __restrict__ qq, const bf16* __restrict__ kk,
    const bf16* __restrict__ vv, const float* __restrict__ hg,
    bf16* __restrict__ y, const float* __restrict__ wout,
    const float* __restrict__ nw, bf16* __restrict__ wout16) {
  const int t = threadIdx.x;
  if (blockIdx.z == 32) {  // convert blocks (96)
    const int cid = blockIdx.x + NUM_HEADS * blockIdx.y;  // 0..95
    for (int j = cid * 256 + t; j < N4WOUT; j += 96 * 256) {
      const int d0 = (j * 4) % D_MODEL;
      const float4 v = ((const float4*)wout)[j];
      const float4 nv = *(const float4*)&nw[d0];
      bf16x4 o;
      o[0] = (bf16)(v.x * nv.x); o[1] = (bf16)(v.y * nv.y);
      o[2] = (bf16)(v.z * nv.z); o[3] = (bf16)(v.w * nv.w);
      ((bf16x4*)wout16)[j] = o;
    }
    return;
  }
  const int nh = blockIdx.x, b = blockIdx.y;
  const int qa = blockIdx.z, qb = 63 - qa;  // paired tiles
  const int l0a = qa * 32, l0b = qb * 32;
  __shared__ __align__(16) float hs[32 + SEQLEN];  // hs[32+d]=h[d], pad=0
  __shared__ __align__(16) bf16 st[8 * 32 * SST];  // 2 S-bufs per wave
  const int n4 = (l0b + 64) >> 2;
  for (int i = t; i < n4; i += 256) {
    float4 val = {0.f, 0.f, 0.f, 0.f};
    if (i >= 8) val = ((const float4*)(hg + nh * SEQLEN))[i - 8];
    ((float4*)hs)[i] = val;
  }
  __syncthreads();

  const int w = t >> 6, lane = t & 63;
  const int l31 = lane & 31, hi = lane >> 5;
  const int row16 = lane & 15, quad = lane >> 4;
  const size_t bn = (size_t)(b * NUM_HEADS + nh);
  const bf16* qp = qq + bn * SEQLEN * 16;
  const bf16* kb = kk + bn * SEQLEN * 16;
  const bf16* vb = vv + bn * 16 * SEQLEN;

  bf16x8 zf;
#pragma unroll
  for (int j = 0; j < 8; ++j) zf[j] = (bf16)0.f;
  const f32x4 zacc4 = {0.f, 0.f, 0.f, 0.f};
  f32x16 zacc16;
#pragma unroll
  for (int j = 0; j < 16; ++j) zacc16[j] = 0.f;

  const bf16x8 qfa = *(const bf16x8*)&qp[(l0a + l31) * 16 + hi * 8];
  const bf16x8 qfb = *(const bf16x8*)&qp[(l0b + l31) * 16 + hi * 8];

  bf16* sw0 = &st[(size_t)w * 2 * 32 * SST];
  bf16* sw1 = sw0 + 32 * SST;

  auto ldK = [&](int mc) { return *(const bf16x8*)&kb[(mc + l31) * 16 + hi * 8]; };
  auto ldV = [&](int mc) { return *(const bf16x8*)&vb[row16 * SEQLEN + mc + quad * 8]; };
  auto wstore = [&](const f32x16& s, const int delta, bf16* buf) {
    const int d0 = 32 + delta + l31 - 4 * hi;
#pragma unroll
    for (int g = 0; g < 4; ++g) {
      const float* hp = &hs[d0 - 8 * g - 3];
      bf16x4 pk;
      pk[0] = (bf16)(s[4 * g + 0] * hp[3]);
      pk[1] = (bf16)(s[4 * g + 1] * hp[2]);
      pk[2] = (bf16)(s[4 * g + 2] * hp[1]);
      pk[3] = (bf16)(s[4 * g + 3] * hp[0]);
      *(bf16x4*)&buf[l31 * SST + 8 * g + 4 * hi] = pk;
    }
  };
  auto pv = [&](const bf16* buf, const bf16x8 vf, f32x4& o0, f32x4& o1) {
    const bf16x8 sf0 = *(const bf16x8*)&buf[row16 * SST + quad * 8];
    const bf16x8 sf1 = *(const bf16x8*)&buf[(row16 + 16) * SST + quad * 8];
    o0 = __builtin_amdgcn_mfma_f32_16x16x32_bf16(sf0, vf, o0, 0, 0, 0);
    o1 = __builtin_amdgcn_mfma_f32_16x16x32_bf16(sf1, vf, o1, 0, 0, 0);
  };

  auto run_pass = [&](const bf16x8& qf, const int l0, const int mc0,
                      f32x4& o0, f32x4& o1) {
    int mc = mc0;
    if (mc > l0) return;
    bf16x8 k0 = ldK(mc);
    bf16x8 vf0 = ldV(mc);
    f32x16 s0 = __builtin_amdgcn_mfma_f32_32x32x16_bf16(k0, qf, zacc16, 0, 0, 0);
    bf16x8 kf1 = zf, vf1 = zf;
    if (mc + 128 <= l0) { kf1 = ldK(mc + 128); vf1 = ldV(mc + 128); }
    wstore(s0, l0 - mc, sw0);
    int p = 0;
    for (; mc + 128 <= l0; mc += 128) {
      bf16x8 kf2 = zf, vf2 = zf;
      if (mc + 256 <= l0) { kf2 = ldK(mc + 256); vf2 = ldV(mc + 256); }
      f32x16 s2 =
          __builtin_amdgcn_mfma_f32_32x32x16_bf16(kf1, qf, zacc16, 0, 0, 0);
      asm volatile("s_waitcnt lgkmcnt(0)" ::: "memory");
      pv(p ? sw1 : sw0, vf0, o0, o1);
      wstore(s2, l0 - (mc + 128), p ? sw0 : sw1);
      p ^= 1;
      kf1 = kf2; vf0 = vf1; vf1 = vf2;
    }
    asm volatile("s_waitcnt lgkmcnt(0)" ::: "memory");
    pv(p ? sw1 : sw0, vf0, o0, o1);
    asm volatile("" ::: "memory");
  };

  f32x4 o0a = zacc4, o1a = zacc4, o0b = zacc4, o1b = zacc4;
  run_pass(qfa, l0a, w * 32, o0a, o1a);
  const int j0 = ((w - qa - 1) % 4 + 4) % 4;
  run_pass(qfb, l0b, j0 * 32, o0b, o1b);

  // epilogue: two phases reusing st as 4 x (32x16 f32) reduction buffers
  float* ob = (float*)&st[(size_t)w * 2 * 32 * SST];
#pragma unroll
  for (int phase = 0; phase < 2; ++phase) {
    const f32x4& p0 = phase ? o0b : o0a;
    const f32x4& p1 = phase ? o1b : o1a;
    const int lt = phase ? l0b : l0a;
    __syncthreads();
#pragma unroll
    for (int r = 0; r < 4; ++r) {
      ob[(quad * 4 + r) * 16 + row16] = p0[r];
      ob[(quad * 4 + r + 16) * 16 + row16] = p1[r];
    }
    __syncthreads();
    for (int i = t; i < 32 * 16; i += 256) {
      const int l = i >> 4, j = i & 15;
      float sum = 0.f;
#pragma unroll
      for (int ww = 0; ww < 4; ++ww)
        sum += ((const float*)&st[(size_t)ww * 2 * 32 * SST])[l * 16 + j];
      y[((size_t)(b * SEQLEN + lt + l) * NUM_HEADS + nh) * 16 + j] = (bf16)sum;
    }
  }
}

// ---------------------------------------------------------------------------
extern "C" void kernel_launch(void* const* d_in, const int* in_sizes, int n_in,
                              void* d_out, int out_size, void* d_ws,
                              size_t ws_size, hipStream_t stream) {
  const float* inputs = (const float*)d_in[0];
  const float* w_in = (const float*)d_in[1];
  const float* b_in = (const float*)d_in[2];
  const float* w_sf = (const float*)d_in[3];
  const float* b_sf = (const float*)d_in[4];
  const float* hb = (const float*)d_in[5];
  const float* norm_w = (const float*)d_in[6];
  const float* w_out = (const float*)d_in[7];
  const float* b_out = (const float*)d_in[8];

  // ws plan (37.8 MB), region lifetimes:
  //   u   18.9 MB : GEMM1 out -> dead after conv_qkv; reused for
  //                 wout16 (+0, 1.2MB, written during attn), y16 (+9MB)
  //   v    6.3 MB : V
  //   A    6.3 MB : in16 (GEMM1 A) -> k16 (attn) -> dead
  //   B    6.3 MB : win16 (GEMM1 W, 3.5MB) -> q16 (attn)
  char* ws = (char*)d_ws;
  const size_t U_B = (size_t)M_ROWS * INNER * 2;
  const size_t V_B = (size_t)BATCH * NUM_HEADS * HEAD_CH * SEQLEN * 2;
  const size_t SLOT_B = (size_t)M_ROWS * D_MODEL * 2;
  bf16* u = (bf16*)(ws);
  bf16* wout16 = (bf16*)(ws);                    // u region, after conv
  bf16* y16 = (bf16*)(ws + (9 << 20));           // u region +9MB
  bf16* v = (bf16*)(ws + U_B);
  bf16* in16 = (bf16*)(ws + U_B + V_B);          // A
  bf16* k16 = in16;                              // A after GEMM1
  bf16* win16 = (bf16*)(ws + U_B + V_B + SLOT_B);// B
  bf16* q16 = win16;                             // B after GEMM1
  float* out = (float*)d_out;

  const int n4_in = M_ROWS * D_MODEL / 4;
  const int n4_win = INNER * D_MODEL / 4;
  hipLaunchKernelGGL(cvt2_f32_bf16, dim3((n4_in + n4_win + 255) / 256),
                     dim3(256), 0, stream, inputs, in16, n4_in, w_in, win16,
                     n4_win);

  // gemm1: 128x128 m97 geometry + XCD swizzle (576 blocks, %8==0)
  hipLaunchKernelGGL((gemm_bt<128, 128, 64, INNER, bf16>), dim3(32, 18),
                     dim3(256), 0, stream, in16, win16, b_in, u, 768);
  hipLaunchKernelGGL(conv_qkv, dim3(48, 2, 16), dim3(256), 0, stream, u, w_sf,
                     b_sf, q16, k16, v);
  // attn + w_out*nw convert fused on z (blockIdx.z == 32)
  hipLaunchKernelGGL(attn_kernel, dim3(48, 2, 33), dim3(256), 0, stream, q16,
                     k16, v, hb, y16, w_out, norm_w, wout16);
  // gemm2 + fused RMSNorm + skip, BK=64 (768 blocks, %8==0)
  hipLaunchKernelGGL(gemm_rms, dim3(64, 12), dim3(256), 0, stream, y16, wout16,
                     b_out, inputs, out);
}